// Round 1
// baseline (2814.316 us; speedup 1.0000x reference)
//
#include <hip/hip_runtime.h>
#include <math.h>

// GlobalAdaptiveDecoder: B=32 S=64 D=512 H=8 DK=DV=64 NR=196 L=6 VOCAB=10000
// Round 1: correct fp32 implementation. GEMMs via generic z-batched tiled kernel,
// fused self-attn, 2-kernel cross-attn. All fp32 -> numerics far inside threshold.

#define Bz 32
#define Sz 64
#define Dz 512
#define Hz 8
#define NRz 196
#define Lz 6
#define VOC 10000
#define S2 (512*512)

// ---------------------------------------------------------------------------
// Generic fp32 GEMM: C[z] = A[z] @ B[z] (+bias). 64x64 tile, BK=16, 256 thr.
// z selects among A0/A1/A2 and B0/B1/B2 (z%3) with optional B stride (z/3)*bz;
// C advances z*cz. Covers qkv (z=3), kc/vc (z=2, different A!), gq-all (z=6).
// ---------------------------------------------------------------------------
#define BKk 16
__global__ __launch_bounds__(256) void gemm_k(
    const float* __restrict__ A0, const float* __restrict__ A1, const float* __restrict__ A2,
    const float* __restrict__ B0, const float* __restrict__ B1, const float* __restrict__ B2,
    long bz, float* __restrict__ C, long cz,
    int M, int N, int K, const float* __restrict__ bias)
{
    int z = blockIdx.z;
    int zm = z % 3;
    const float* A = (zm == 0) ? A0 : (zm == 1) ? A1 : A2;
    const float* B = ((zm == 0) ? B0 : (zm == 1) ? B1 : B2) + (long)(z / 3) * bz;
    float* Cp = C + (long)z * cz;

    int n0 = blockIdx.x * 64, m0 = blockIdx.y * 64;
    __shared__ float As[BKk][68];   // As[k][m], stride 68 -> 16B-aligned float4 rows, conflict-free
    __shared__ float Bs[BKk][68];   // Bs[k][n]
    int t  = threadIdx.x;
    int tx = t & 15, ty = t >> 4;
    int am = t >> 2, ak = (t & 3) << 2;   // A tile load: row am, col group ak (float4)
    int bk = t >> 4, bn = (t & 15) << 2;  // B tile load: row bk, col group bn (float4)
    float acc[4][4] = {};
    const bool amok = (m0 + am) < M;

    for (int k0 = 0; k0 < K; k0 += BKk) {
        float4 av = make_float4(0.f, 0.f, 0.f, 0.f);
        if (amok) av = *(const float4*)(A + (long)(m0 + am) * K + (k0 + ak));
        float4 bv;
        {
            const float* bp = B + (long)(k0 + bk) * N + (n0 + bn);
            int rem = N - (n0 + bn);
            if (rem >= 4) bv = *(const float4*)bp;
            else {
                bv.x = (rem > 0) ? bp[0] : 0.f;
                bv.y = (rem > 1) ? bp[1] : 0.f;
                bv.z = (rem > 2) ? bp[2] : 0.f;
                bv.w = 0.f;
            }
        }
        __syncthreads();   // previous iteration's compute done before overwrite
        As[ak + 0][am] = av.x;
        As[ak + 1][am] = av.y;
        As[ak + 2][am] = av.z;
        As[ak + 3][am] = av.w;
        *(float4*)&Bs[bk][bn] = bv;
        __syncthreads();
#pragma unroll
        for (int kk = 0; kk < BKk; ++kk) {
            float4 a = *(const float4*)&As[kk][ty << 2];
            float4 b = *(const float4*)&Bs[kk][tx << 2];
            acc[0][0] += a.x * b.x; acc[0][1] += a.x * b.y; acc[0][2] += a.x * b.z; acc[0][3] += a.x * b.w;
            acc[1][0] += a.y * b.x; acc[1][1] += a.y * b.y; acc[1][2] += a.y * b.z; acc[1][3] += a.y * b.w;
            acc[2][0] += a.z * b.x; acc[2][1] += a.z * b.y; acc[2][2] += a.z * b.z; acc[2][3] += a.z * b.w;
            acc[3][0] += a.w * b.x; acc[3][1] += a.w * b.y; acc[3][2] += a.w * b.z; acc[3][3] += a.w * b.w;
        }
    }

#pragma unroll
    for (int i = 0; i < 4; ++i) {
        int m = m0 + (ty << 2) + i;
        if (m >= M) break;
        float* cp = Cp + (long)m * N + n0 + (tx << 2);
        int rem = N - (n0 + (tx << 2));
        float4 o = make_float4(acc[i][0], acc[i][1], acc[i][2], acc[i][3]);
        if (bias) {
            const float* bp2 = bias + n0 + (tx << 2);
            if (rem > 0) o.x += bp2[0];
            if (rem > 1) o.y += bp2[1];
            if (rem > 2) o.z += bp2[2];
            if (rem > 3) o.w += bp2[3];
        }
        if (rem >= 4) *(float4*)cp = o;
        else {
            if (rem > 0) cp[0] = o.x;
            if (rem > 1) cp[1] = o.y;
            if (rem > 2) cp[2] = o.z;
        }
    }
}

// ---------------------------------------------------------------------------
// Embedding + positional encoding (PE in double for fidelity to the f32 ref).
// ---------------------------------------------------------------------------
__global__ __launch_bounds__(256) void embed_pe(const int* __restrict__ x,
                                                const float* __restrict__ emb,
                                                float* __restrict__ act)
{
    long i = (long)blockIdx.x * 256 + threadIdx.x;  // over 2048*512
    int d = (int)(i & 511);
    long tok = i >> 9;
    int s = (int)(tok & 63);
    int id = x[tok];
    int j = d >> 1;
    double ang = (double)s * exp(-log(10000.0) * (2.0 * j) / 512.0);
    float pe = (d & 1) ? (float)cos(ang) : (float)sin(ang);
    act[i] = emb[(long)id * 512 + d] + pe;
}

// ---------------------------------------------------------------------------
// Fused causal self-attention, one block per (b,h), 256 threads, S=64 keys.
// K/V/Q tiles resident in LDS (52 KB). Wave w owns q-rows w*16..w*16+15.
// ---------------------------------------------------------------------------
__global__ __launch_bounds__(256) void self_attn(const float* __restrict__ q,
                                                 const float* __restrict__ k,
                                                 const float* __restrict__ v,
                                                 float* __restrict__ o)
{
    int b = blockIdx.x >> 3, h = blockIdx.x & 7;
    __shared__ float Ks[64][68], Vs[64][68], Qs[64][68];
    int t = threadIdx.x;
    long base = ((long)b * 64) * 512 + h * 64;
    for (int e = t; e < 4096; e += 256) {
        int r = e >> 6, c = e & 63;
        long gidx = base + (long)r * 512 + c;
        Ks[r][c] = k[gidx];
        Vs[r][c] = v[gidx];
        Qs[r][c] = q[gidx];
    }
    __syncthreads();
    int w = t >> 6, lane = t & 63;

    // scores + softmax; P overwrites this wave's own Qs rows
    for (int g4 = 0; g4 < 4; ++g4) {
        int qi0 = w * 16 + g4 * 4;
        float s[4] = {0.f, 0.f, 0.f, 0.f};
#pragma unroll
        for (int d4 = 0; d4 < 16; ++d4) {
            float4 kv = *(const float4*)&Ks[lane][d4 << 2];
#pragma unroll
            for (int r = 0; r < 4; ++r) {
                float4 qv = *(const float4*)&Qs[qi0 + r][d4 << 2];
                s[r] += qv.x * kv.x + qv.y * kv.y + qv.z * kv.z + qv.w * kv.w;
            }
        }
#pragma unroll
        for (int r = 0; r < 4; ++r) {
            int qi = qi0 + r;
            float sv = (lane <= qi) ? s[r] * 0.125f : -INFINITY;
            float m = sv;
            for (int off = 32; off; off >>= 1) m = fmaxf(m, __shfl_xor(m, off));
            float p = __expf(sv - m);   // lane>qi -> exp(-inf)=0
            float sum = p;
            for (int off = 32; off; off >>= 1) sum += __shfl_xor(sum, off);
            Qs[qi][lane] = p / sum;
        }
    }
    __syncthreads();

    // O = P @ V ; wave w handles its own 16 rows, 8 at a time (lane = out dim)
#pragma unroll
    for (int gg = 0; gg < 2; ++gg) {
        int qi0 = w * 16 + gg * 8;
        float acc[8] = {};
        for (int j = 0; j < 64; ++j) {
            float vv = Vs[j][lane];
#pragma unroll
            for (int r = 0; r < 8; ++r) acc[r] += Qs[qi0 + r][j] * vv;
        }
#pragma unroll
        for (int r = 0; r < 8; ++r)
            o[base + (long)(qi0 + r) * 512 + lane] = acc[r];
    }
}

// ---------------------------------------------------------------------------
// Cross-attn part 1: P = softmax((qc + gq) Kc^T / 8), block per (b,h).
// Kc tile (196x64) resident in LDS; 4 q-rows per pass.
// ---------------------------------------------------------------------------
__global__ __launch_bounds__(256) void cross_scores(const float* __restrict__ qc,
                                                    const float* __restrict__ gq,
                                                    const float* __restrict__ kc,
                                                    float* __restrict__ P)
{
    int b = blockIdx.x >> 3, h = blockIdx.x & 7;
    __shared__ float Ks[196][68];
    __shared__ float qv[4][68];
    __shared__ float red[2][4][4];  // [max|sum][wave][r]
    int t = threadIdx.x;
    long kbase = ((long)b * 196) * 512 + h * 64;
    for (int e = t; e < 196 * 64; e += 256) {
        int r = e >> 6, c = e & 63;
        Ks[r][c] = kc[kbase + (long)r * 512 + c];
    }
    int w = t >> 6, lane = t & 63;
    long qbase = ((long)b * 64) * 512 + h * 64;
    long gbase = (long)b * 512 + h * 64;
    long pbase = ((long)(b * 8 + h)) * 64 * 196;
    __syncthreads();

    for (int qb = 0; qb < 16; ++qb) {
        qv[w][lane] = qc[qbase + (long)(qb * 4 + w) * 512 + lane] + gq[gbase + lane];
        __syncthreads();
        float s[4];
        if (t < 196) {
            s[0] = s[1] = s[2] = s[3] = 0.f;
#pragma unroll
            for (int d4 = 0; d4 < 16; ++d4) {
                float4 kvv = *(const float4*)&Ks[t][d4 << 2];
#pragma unroll
                for (int r = 0; r < 4; ++r) {
                    float4 qf = *(const float4*)&qv[r][d4 << 2];
                    s[r] += qf.x * kvv.x + qf.y * kvv.y + qf.z * kvv.z + qf.w * kvv.w;
                }
            }
#pragma unroll
            for (int r = 0; r < 4; ++r) s[r] *= 0.125f;
        } else {
            s[0] = s[1] = s[2] = s[3] = -INFINITY;
        }
        float m[4], p[4], su[4];
#pragma unroll
        for (int r = 0; r < 4; ++r) {
            m[r] = s[r];
            for (int off = 32; off; off >>= 1) m[r] = fmaxf(m[r], __shfl_xor(m[r], off));
        }
        if (lane == 0) { for (int r = 0; r < 4; ++r) red[0][w][r] = m[r]; }
        __syncthreads();
#pragma unroll
        for (int r = 0; r < 4; ++r) {
            float mm = fmaxf(fmaxf(red[0][0][r], red[0][1][r]), fmaxf(red[0][2][r], red[0][3][r]));
            p[r] = (t < 196) ? __expf(s[r] - mm) : 0.f;
            su[r] = p[r];
            for (int off = 32; off; off >>= 1) su[r] += __shfl_xor(su[r], off);
        }
        if (lane == 0) { for (int r = 0; r < 4; ++r) red[1][w][r] = su[r]; }
        __syncthreads();
        if (t < 196) {
#pragma unroll
            for (int r = 0; r < 4; ++r) {
                float tot = red[1][0][r] + red[1][1][r] + red[1][2][r] + red[1][3][r];
                P[pbase + (long)(qb * 4 + r) * 196 + t] = p[r] / tot;
            }
        }
        __syncthreads();  // protect qv / red for next iteration
    }
}

// ---------------------------------------------------------------------------
// Cross-attn part 2: O = P @ Vc, block per (b,h). Vc tile resident in LDS,
// P streamed in 64x14 chunks; 4x4 register micro-tile per thread.
// ---------------------------------------------------------------------------
__global__ __launch_bounds__(256) void cross_pv(const float* __restrict__ P,
                                                const float* __restrict__ vc,
                                                float* __restrict__ o)
{
    int b = blockIdx.x >> 3, h = blockIdx.x & 7;
    __shared__ float Vs[196][68];
    __shared__ float Ps[64][18];
    int t = threadIdx.x;
    int tx = t & 15, ty = t >> 4;
    long vbase = ((long)b * 196) * 512 + h * 64;
    for (int e = t; e < 196 * 64; e += 256) {
        int r = e >> 6, c = e & 63;
        Vs[r][c] = vc[vbase + (long)r * 512 + c];
    }
    long pbase = ((long)(b * 8 + h)) * 64 * 196;
    float acc[4][4] = {};
    for (int k0 = 0; k0 < 196; k0 += 14) {
        for (int e = t; e < 64 * 14; e += 256) {
            int m = e / 14, kk = e - m * 14;
            Ps[m][kk] = P[pbase + (long)m * 196 + k0 + kk];
        }
        __syncthreads();   // first one also covers Vs staging
#pragma unroll
        for (int kk = 0; kk < 14; ++kk) {
            float a0 = Ps[(ty << 2) + 0][kk];
            float a1 = Ps[(ty << 2) + 1][kk];
            float a2 = Ps[(ty << 2) + 2][kk];
            float a3 = Ps[(ty << 2) + 3][kk];
            float4 bv = *(const float4*)&Vs[k0 + kk][tx << 2];
            acc[0][0] += a0 * bv.x; acc[0][1] += a0 * bv.y; acc[0][2] += a0 * bv.z; acc[0][3] += a0 * bv.w;
            acc[1][0] += a1 * bv.x; acc[1][1] += a1 * bv.y; acc[1][2] += a1 * bv.z; acc[1][3] += a1 * bv.w;
            acc[2][0] += a2 * bv.x; acc[2][1] += a2 * bv.y; acc[2][2] += a2 * bv.z; acc[2][3] += a2 * bv.w;
            acc[3][0] += a3 * bv.x; acc[3][1] += a3 * bv.y; acc[3][2] += a3 * bv.z; acc[3][3] += a3 * bv.w;
        }
        __syncthreads();
    }
    long obase = ((long)b * 64) * 512 + h * 64;
#pragma unroll
    for (int i = 0; i < 4; ++i) {
        float4 ov = make_float4(acc[i][0], acc[i][1], acc[i][2], acc[i][3]);
        *(float4*)&o[obase + (long)((ty << 2) + i) * 512 + (tx << 2)] = ov;
    }
}

// ---------------------------------------------------------------------------
// Row softmax over VOCAB=10000, one block (256 thr) per row, values in regs.
// ---------------------------------------------------------------------------
__global__ __launch_bounds__(256) void softmax_rows(float* __restrict__ out)
{
    __shared__ float red[8];
    long row = blockIdx.x;
    float* p = out + row * 10000L;
    int t = threadIdx.x;
    int w = t >> 6, lane = t & 63;
    float vals[40];
    float mx = -INFINITY;
#pragma unroll
    for (int ii = 0; ii < 40; ++ii) {
        int c = t + (ii << 8);
        if (c < 10000) { float v = p[c]; vals[ii] = v; mx = fmaxf(mx, v); }
        else vals[ii] = -INFINITY;
    }
    for (int off = 32; off; off >>= 1) mx = fmaxf(mx, __shfl_xor(mx, off));
    if (lane == 0) red[w] = mx;
    __syncthreads();
    mx = fmaxf(fmaxf(red[0], red[1]), fmaxf(red[2], red[3]));
    float s = 0.f;
#pragma unroll
    for (int ii = 0; ii < 40; ++ii) {
        float e = __expf(vals[ii] - mx);  // -inf slots -> 0
        vals[ii] = e;
        s += e;
    }
    for (int off = 32; off; off >>= 1) s += __shfl_xor(s, off);
    if (lane == 0) red[4 + w] = s;
    __syncthreads();
    s = red[4] + red[5] + red[6] + red[7];
    float inv = 1.0f / s;
#pragma unroll
    for (int ii = 0; ii < 40; ++ii) {
        int c = t + (ii << 8);
        if (c < 10000) p[c] = vals[ii] * inv;
    }
}

// ---------------------------------------------------------------------------
extern "C" void kernel_launch(void* const* d_in, const int* in_sizes, int n_in,
                              void* d_out, int out_size, void* d_ws, size_t ws_size,
                              hipStream_t stream)
{
    const int*   x    = (const int*)d_in[0];
    const float* Kin  = (const float*)d_in[1];
    const float* Vin  = (const float*)d_in[2];
    const float* g    = (const float*)d_in[3];
    const float* emb  = (const float*)d_in[5];
    const float* Wq_s = (const float*)d_in[6];
    const float* Wk_s = (const float*)d_in[7];
    const float* Wv_s = (const float*)d_in[8];
    const float* Wo_s = (const float*)d_in[9];
    const float* Wq_c = (const float*)d_in[10];
    const float* Wg_c = (const float*)d_in[11];
    const float* Wk_c = (const float*)d_in[12];
    const float* Wv_c = (const float*)d_in[13];
    const float* Wo_c = (const float*)d_in[14];
    const float* Wf   = (const float*)d_in[15];
    const float* bf   = (const float*)d_in[16];
    float* out = (float*)d_out;
    float* ws  = (float*)d_ws;

    // workspace layout (floats): ~60 MB total
    float* act   = ws;                    // [2048,512]
    float* qb    = ws + 1 * 1048576;      // [2048,512]
    float* kb    = ws + 2 * 1048576;
    float* vb    = ws + 3 * 1048576;
    float* attno = ws + 4 * 1048576;
    float* kc    = ws + 5 * 1048576;      // [6272,512]
    float* vc    = kc + 3211264;          // [6272,512]
    float* gq    = vc + 3211264;          // [6,32,512]
    float* P     = gq + 98304;            // [32,8,64,196]

    embed_pe<<<4096, 256, 0, stream>>>(x, emb, act);

    // all 6 layers of g @ Wg_c in one launch (z=0..5 strides through Wg_c)
    gemm_k<<<dim3(8, 1, 6), 256, 0, stream>>>(
        g, g, g, Wg_c, Wg_c + S2, Wg_c + 2 * S2, 3L * S2,
        gq, 16384L, 32, 512, 512, nullptr);

    for (int l = 0; l < Lz; ++l) {
        long wo = (long)l * S2;
        // q,k,v projections in one z=3 launch
        gemm_k<<<dim3(8, 32, 3), 256, 0, stream>>>(
            act, act, act, Wq_s + wo, Wk_s + wo, Wv_s + wo, 0L,
            qb, 1048576L, 2048, 512, 512, nullptr);
        self_attn<<<256, 256, 0, stream>>>(qb, kb, vb, attno);
        gemm_k<<<dim3(8, 32, 1), 256, 0, stream>>>(
            attno, attno, attno, Wo_s + wo, Wo_s + wo, Wo_s + wo, 0L,
            act, 0L, 2048, 512, 512, nullptr);
        // cross K/V projections (different A per z!)
        gemm_k<<<dim3(8, 98, 2), 256, 0, stream>>>(
            Kin, Vin, Vin, Wk_c + wo, Wv_c + wo, Wv_c + wo, 0L,
            kc, 3211264L, 6272, 512, 512, nullptr);
        // qc = act @ Wq_c
        gemm_k<<<dim3(8, 32, 1), 256, 0, stream>>>(
            act, act, act, Wq_c + wo, Wq_c + wo, Wq_c + wo, 0L,
            qb, 0L, 2048, 512, 512, nullptr);
        cross_scores<<<256, 256, 0, stream>>>(qb, gq + (long)l * 16384, kc, P);
        cross_pv<<<256, 256, 0, stream>>>(P, vc, attno);
        gemm_k<<<dim3(8, 32, 1), 256, 0, stream>>>(
            attno, attno, attno, Wo_c + wo, Wo_c + wo, Wo_c + wo, 0L,
            act, 0L, 2048, 512, 512, nullptr);
    }

    // logits + softmax
    gemm_k<<<dim3(157, 32, 1), 256, 0, stream>>>(
        act, act, act, Wf, Wf, Wf, 0L,
        out, 0L, 2048, 10000, 512, bf);
    softmax_rows<<<2048, 256, 0, stream>>>(out);
}

// Round 2
// 1461.369 us; speedup vs baseline: 1.9258x; 1.9258x over previous
//
#include <hip/hip_runtime.h>
#include <math.h>

// GlobalAdaptiveDecoder: B=32 S=64 D=512 H=8 DK=DV=64 NR=196 L=6 VOCAB=10000
// Round 2: bf16 MFMA GEMMs (m97 recipe: 128x128 tile, BK=32, global_load_lds
// width-16, ds_read_b128 frags, B pre-transposed to [N,K] bf16). Attention
// softmax stays fp32. Activations flow as bf16 between GEMMs.

#define S2 (512*512)
typedef unsigned short ushort_t;
typedef unsigned int u32;
typedef __attribute__((ext_vector_type(8))) short short8;
typedef __attribute__((ext_vector_type(4))) float f32x4;

__device__ __forceinline__ ushort_t f2b(float f) {
    union { float f; u32 u; } v; v.f = f;
    u32 r = (v.u + 0x7fffu + ((v.u >> 16) & 1u)) >> 16;
    return (ushort_t)r;
}

__device__ __forceinline__ void glds16(const void* g, void* l) {
    __builtin_amdgcn_global_load_lds((const __attribute__((address_space(1))) u32*)g,
                                     (__attribute__((address_space(3))) u32*)l,
                                     16, 0, 0);
}

// ---------------------------------------------------------------------------
// bf16 MFMA GEMM: C[z] = A[z] @ Bt[z]^T. A:[M,K] bf16, Bt:[N,K] bf16.
// 128x128 tile, BK=32, 256 thr (4 waves, each 64x64 via 4x4 16x16x32 MFMAs).
// z%3 selects A/Bt pair; Bt advances (z/3)*bz. Optional fp32 and bf16 outputs.
// M, N(staging) must be multiples of 128; store guarded by col<N.
// ---------------------------------------------------------------------------
__global__ __launch_bounds__(256) void gemm_bt(
    const ushort_t* __restrict__ A0, const ushort_t* __restrict__ A1, const ushort_t* __restrict__ A2,
    const ushort_t* __restrict__ B0, const ushort_t* __restrict__ B1, const ushort_t* __restrict__ B2,
    long bz, float* __restrict__ Cf, long czf, ushort_t* __restrict__ Cb, long czb,
    int M, int N, int Npad, int K, const float* __restrict__ bias)
{
    int z = blockIdx.z, zm = z % 3;
    const ushort_t* A = (zm == 0) ? A0 : (zm == 1) ? A1 : A2;
    const ushort_t* B = ((zm == 0) ? B0 : (zm == 1) ? B1 : B2) + (long)(z / 3) * bz;

    int m0 = blockIdx.y * 128, n0 = blockIdx.x * 128;
    __shared__ ushort_t As[128 * 32];
    __shared__ ushort_t Bs[128 * 32];
    int t = threadIdx.x;
    // staging: chunk c in [0,512): row=c>>2, kg=(c&3)*8 ; thread t covers c=t and c=t+256
    int sr = t >> 2, sk = (t & 3) * 8;

    f32x4 acc[4][4];
#pragma unroll
    for (int i = 0; i < 4; ++i)
#pragma unroll
        for (int j = 0; j < 4; ++j) acc[i][j] = (f32x4){0.f, 0.f, 0.f, 0.f};

    int wv = t >> 6, lane = t & 63;
    int wr = (wv >> 1) * 64, wc = (wv & 1) * 64;
    int lr = lane & 15, lq = lane >> 4;

    for (int k0 = 0; k0 < K; k0 += 32) {
        glds16(A + (long)(m0 + sr) * K + k0 + sk,      (void*)(As + t * 8));
        glds16(A + (long)(m0 + sr + 64) * K + k0 + sk, (void*)(As + (t + 256) * 8));
        glds16(B + (long)(n0 + sr) * K + k0 + sk,      (void*)(Bs + t * 8));
        glds16(B + (long)(n0 + sr + 64) * K + k0 + sk, (void*)(Bs + (t + 256) * 8));
        __syncthreads();
        short8 af[4], bfr[4];
#pragma unroll
        for (int i = 0; i < 4; ++i)
            af[i] = *(const short8*)&As[(wr + i * 16 + lr) * 32 + lq * 8];
#pragma unroll
        for (int j = 0; j < 4; ++j)
            bfr[j] = *(const short8*)&Bs[(wc + j * 16 + lr) * 32 + lq * 8];
#pragma unroll
        for (int i = 0; i < 4; ++i)
#pragma unroll
            for (int j = 0; j < 4; ++j)
                acc[i][j] = __builtin_amdgcn_mfma_f32_16x16x32_bf16(af[i], bfr[j], acc[i][j], 0, 0, 0);
        __syncthreads();
    }

#pragma unroll
    for (int i = 0; i < 4; ++i) {
#pragma unroll
        for (int j = 0; j < 4; ++j) {
            int row = m0 + wr + i * 16 + lq * 4;
            int col = n0 + wc + j * 16 + lr;
            if (col < N) {
                float bv = bias ? bias[col] : 0.f;
#pragma unroll
                for (int r = 0; r < 4; ++r) {
                    float val = acc[i][j][r] + bv;
                    long idx = (long)(row + r) * N + col;
                    if (Cf) Cf[(long)z * czf + idx] = val;
                    if (Cb) Cb[(long)z * czb + idx] = f2b(val);
                }
            }
        }
    }
}

// ---------------------------------------------------------------------------
// fp32 GEMM (kept for tiny gq = g @ Wg_c, M=32). 64x64 tile, BK=16.
// ---------------------------------------------------------------------------
#define BKk 16
__global__ __launch_bounds__(256) void gemm_k(
    const float* __restrict__ Ain, const float* __restrict__ Bin,
    long bz, float* __restrict__ C, long cz, int M, int N, int K)
{
    int z = blockIdx.z;
    const float* A = Ain;
    const float* B = Bin + (long)z * bz;
    float* Cp = C + (long)z * cz;
    int n0 = blockIdx.x * 64, m0 = blockIdx.y * 64;
    __shared__ float As[BKk][68];
    __shared__ float Bs[BKk][68];
    int t = threadIdx.x;
    int tx = t & 15, ty = t >> 4;
    int am = t >> 2, ak = (t & 3) << 2;
    int bk = t >> 4, bn = (t & 15) << 2;
    float acc[4][4] = {};
    const bool amok = (m0 + am) < M;

    for (int k0 = 0; k0 < K; k0 += BKk) {
        float4 av = make_float4(0.f, 0.f, 0.f, 0.f);
        if (amok) av = *(const float4*)(A + (long)(m0 + am) * K + (k0 + ak));
        float4 bv = *(const float4*)(B + (long)(k0 + bk) * N + (n0 + bn));
        __syncthreads();
        As[ak + 0][am] = av.x; As[ak + 1][am] = av.y;
        As[ak + 2][am] = av.z; As[ak + 3][am] = av.w;
        *(float4*)&Bs[bk][bn] = bv;
        __syncthreads();
#pragma unroll
        for (int kk = 0; kk < BKk; ++kk) {
            float4 a = *(const float4*)&As[kk][ty << 2];
            float4 b = *(const float4*)&Bs[kk][tx << 2];
            acc[0][0] += a.x * b.x; acc[0][1] += a.x * b.y; acc[0][2] += a.x * b.z; acc[0][3] += a.x * b.w;
            acc[1][0] += a.y * b.x; acc[1][1] += a.y * b.y; acc[1][2] += a.y * b.z; acc[1][3] += a.y * b.w;
            acc[2][0] += a.z * b.x; acc[2][1] += a.z * b.y; acc[2][2] += a.z * b.z; acc[2][3] += a.z * b.w;
            acc[3][0] += a.w * b.x; acc[3][1] += a.w * b.y; acc[3][2] += a.w * b.z; acc[3][3] += a.w * b.w;
        }
    }
#pragma unroll
    for (int i = 0; i < 4; ++i) {
        int m = m0 + (ty << 2) + i;
        if (m >= M) break;
        *(float4*)(Cp + (long)m * N + n0 + (tx << 2)) =
            make_float4(acc[i][0], acc[i][1], acc[i][2], acc[i][3]);
    }
}

// ---------------------------------------------------------------------------
// Weight convert+transpose: 8 mats x 6 layers of [512,512] f32 -> [512,512] bf16^T
// ---------------------------------------------------------------------------
__global__ __launch_bounds__(256) void convw_t(
    const float* __restrict__ W0, const float* __restrict__ W1, const float* __restrict__ W2,
    const float* __restrict__ W3, const float* __restrict__ W4, const float* __restrict__ W5,
    const float* __restrict__ W6, const float* __restrict__ W7, ushort_t* __restrict__ out)
{
    int z = blockIdx.z, mat = z % 8, l = z / 8;
    const float* src = (mat == 0) ? W0 : (mat == 1) ? W1 : (mat == 2) ? W2 : (mat == 3) ? W3 :
                       (mat == 4) ? W4 : (mat == 5) ? W5 : (mat == 6) ? W6 : W7;
    src += (long)l * S2;
    ushort_t* dst = out + (long)(mat * 6 + l) * S2;
    __shared__ float tile[64][65];
    int k0 = blockIdx.y * 64, n0 = blockIdx.x * 64;
    int t = threadIdx.x;
    for (int e = t; e < 4096; e += 256) {
        int r = e >> 6, c = e & 63;
        tile[r][c] = src[(long)(k0 + r) * 512 + n0 + c];
    }
    __syncthreads();
    for (int e = t; e < 4096; e += 256) {
        int r = e >> 6, c = e & 63;   // r = n-local, c = k-local
        dst[(long)(n0 + r) * 512 + k0 + c] = f2b(tile[c][r]);
    }
}

// Wf [512,10000] f32 -> Wf_t [10112,512] bf16 (rows >= 10000 zero-padded)
__global__ __launch_bounds__(256) void convwf_t(const float* __restrict__ Wf,
                                               ushort_t* __restrict__ out)
{
    __shared__ float tile[64][65];
    int n0 = blockIdx.x * 64, k0 = blockIdx.y * 64;
    int t = threadIdx.x;
    for (int e = t; e < 4096; e += 256) {
        int r = e >> 6, c = e & 63;
        int n = n0 + c;
        tile[r][c] = (n < 10000) ? Wf[(long)(k0 + r) * 10000 + n] : 0.f;
    }
    __syncthreads();
    for (int e = t; e < 4096; e += 256) {
        int r = e >> 6, c = e & 63;
        out[(long)(n0 + r) * 512 + k0 + c] = f2b(tile[c][r]);
    }
}

// elementwise f32 -> bf16 for Kin / Vin (3211264 elements each)
__global__ __launch_bounds__(256) void conv2(const float* __restrict__ a, const float* __restrict__ b,
                                             ushort_t* __restrict__ oa, ushort_t* __restrict__ ob)
{
    const float* s = blockIdx.y ? b : a;
    ushort_t* o = blockIdx.y ? ob : oa;
    long i = ((long)blockIdx.x * 256 + threadIdx.x) * 4;
    float4 v = *(const float4*)(s + i);
    ushort4 u;
    u.x = f2b(v.x); u.y = f2b(v.y); u.z = f2b(v.z); u.w = f2b(v.w);
    *(ushort4*)(o + i) = u;
}

// ---------------------------------------------------------------------------
// Embedding + positional encoding -> bf16 activations
// ---------------------------------------------------------------------------
__global__ __launch_bounds__(256) void embed_pe(const int* __restrict__ x,
                                                const float* __restrict__ emb,
                                                ushort_t* __restrict__ act)
{
    long i = (long)blockIdx.x * 256 + threadIdx.x;
    int d = (int)(i & 511);
    long tok = i >> 9;
    int s = (int)(tok & 63);
    int id = x[tok];
    int j = d >> 1;
    double ang = (double)s * exp(-log(10000.0) * (2.0 * j) / 512.0);
    float pe = (d & 1) ? (float)cos(ang) : (float)sin(ang);
    act[i] = f2b(emb[(long)id * 512 + d] + pe);
}

// ---------------------------------------------------------------------------
// Fused causal self-attention (fp32 math), bf16 output. Block per (b,h).
// ---------------------------------------------------------------------------
__global__ __launch_bounds__(256) void self_attn(const float* __restrict__ q,
                                                 const float* __restrict__ k,
                                                 const float* __restrict__ v,
                                                 ushort_t* __restrict__ o)
{
    int b = blockIdx.x >> 3, h = blockIdx.x & 7;
    __shared__ float Ks[64][68], Vs[64][68], Qs[64][68];
    int t = threadIdx.x;
    long base = ((long)b * 64) * 512 + h * 64;
    for (int e = t; e < 4096; e += 256) {
        int r = e >> 6, c = e & 63;
        long gidx = base + (long)r * 512 + c;
        Ks[r][c] = k[gidx];
        Vs[r][c] = v[gidx];
        Qs[r][c] = q[gidx];
    }
    __syncthreads();
    int w = t >> 6, lane = t & 63;

    for (int g4 = 0; g4 < 4; ++g4) {
        int qi0 = w * 16 + g4 * 4;
        float s[4] = {0.f, 0.f, 0.f, 0.f};
#pragma unroll
        for (int d4 = 0; d4 < 16; ++d4) {
            float4 kv = *(const float4*)&Ks[lane][d4 << 2];
#pragma unroll
            for (int r = 0; r < 4; ++r) {
                float4 qv = *(const float4*)&Qs[qi0 + r][d4 << 2];
                s[r] += qv.x * kv.x + qv.y * kv.y + qv.z * kv.z + qv.w * kv.w;
            }
        }
#pragma unroll
        for (int r = 0; r < 4; ++r) {
            int qi = qi0 + r;
            float sv = (lane <= qi) ? s[r] * 0.125f : -INFINITY;
            float m = sv;
            for (int off = 32; off; off >>= 1) m = fmaxf(m, __shfl_xor(m, off));
            float p = __expf(sv - m);
            float sum = p;
            for (int off = 32; off; off >>= 1) sum += __shfl_xor(sum, off);
            Qs[qi][lane] = p / sum;
        }
    }
    __syncthreads();

#pragma unroll
    for (int gg = 0; gg < 2; ++gg) {
        int qi0 = w * 16 + gg * 8;
        float acc[8] = {};
        for (int j = 0; j < 64; ++j) {
            float vv = Vs[j][lane];
#pragma unroll
            for (int r = 0; r < 8; ++r) acc[r] += Qs[qi0 + r][j] * vv;
        }
#pragma unroll
        for (int r = 0; r < 8; ++r)
            o[base + (long)(qi0 + r) * 512 + lane] = f2b(acc[r]);
    }
}

// ---------------------------------------------------------------------------
// Cross-attn part 1: P = softmax((qc + gq) Kc^T / 8), block per (b,h).
// ---------------------------------------------------------------------------
__global__ __launch_bounds__(256) void cross_scores(const float* __restrict__ qc,
                                                    const float* __restrict__ gq,
                                                    const float* __restrict__ kc,
                                                    float* __restrict__ P)
{
    int b = blockIdx.x >> 3, h = blockIdx.x & 7;
    __shared__ float Ks[196][68];
    __shared__ float qv[4][68];
    __shared__ float red[2][4][4];
    int t = threadIdx.x;
    long kbase = ((long)b * 196) * 512 + h * 64;
    for (int e = t; e < 196 * 64; e += 256) {
        int r = e >> 6, c = e & 63;
        Ks[r][c] = kc[kbase + (long)r * 512 + c];
    }
    int w = t >> 6, lane = t & 63;
    long qbase = ((long)b * 64) * 512 + h * 64;
    long gbase = (long)b * 512 + h * 64;
    long pbase = ((long)(b * 8 + h)) * 64 * 196;
    __syncthreads();

    for (int qb = 0; qb < 16; ++qb) {
        qv[w][lane] = qc[qbase + (long)(qb * 4 + w) * 512 + lane] + gq[gbase + lane];
        __syncthreads();
        float s[4];
        if (t < 196) {
            s[0] = s[1] = s[2] = s[3] = 0.f;
#pragma unroll
            for (int d4 = 0; d4 < 16; ++d4) {
                float4 kvv = *(const float4*)&Ks[t][d4 << 2];
#pragma unroll
                for (int r = 0; r < 4; ++r) {
                    float4 qf = *(const float4*)&qv[r][d4 << 2];
                    s[r] += qf.x * kvv.x + qf.y * kvv.y + qf.z * kvv.z + qf.w * kvv.w;
                }
            }
#pragma unroll
            for (int r = 0; r < 4; ++r) s[r] *= 0.125f;
        } else {
            s[0] = s[1] = s[2] = s[3] = -INFINITY;
        }
        float m[4], p[4], su[4];
#pragma unroll
        for (int r = 0; r < 4; ++r) {
            m[r] = s[r];
            for (int off = 32; off; off >>= 1) m[r] = fmaxf(m[r], __shfl_xor(m[r], off));
        }
        if (lane == 0) { for (int r = 0; r < 4; ++r) red[0][w][r] = m[r]; }
        __syncthreads();
#pragma unroll
        for (int r = 0; r < 4; ++r) {
            float mm = fmaxf(fmaxf(red[0][0][r], red[0][1][r]), fmaxf(red[0][2][r], red[0][3][r]));
            p[r] = (t < 196) ? __expf(s[r] - mm) : 0.f;
            su[r] = p[r];
            for (int off = 32; off; off >>= 1) su[r] += __shfl_xor(su[r], off);
        }
        if (lane == 0) { for (int r = 0; r < 4; ++r) red[1][w][r] = su[r]; }
        __syncthreads();
        if (t < 196) {
#pragma unroll
            for (int r = 0; r < 4; ++r) {
                float tot = red[1][0][r] + red[1][1][r] + red[1][2][r] + red[1][3][r];
                P[pbase + (long)(qb * 4 + r) * 196 + t] = p[r] / tot;
            }
        }
        __syncthreads();
    }
}

// ---------------------------------------------------------------------------
// Cross-attn part 2: O = P @ Vc -> bf16, block per (b,h).
// ---------------------------------------------------------------------------
__global__ __launch_bounds__(256) void cross_pv(const float* __restrict__ P,
                                                const float* __restrict__ vc,
                                                ushort_t* __restrict__ o)
{
    int b = blockIdx.x >> 3, h = blockIdx.x & 7;
    __shared__ float Vs[196][68];
    __shared__ float Ps[64][18];
    int t = threadIdx.x;
    int tx = t & 15, ty = t >> 4;
    long vbase = ((long)b * 196) * 512 + h * 64;
    for (int e = t; e < 196 * 64; e += 256) {
        int r = e >> 6, c = e & 63;
        Vs[r][c] = vc[vbase + (long)r * 512 + c];
    }
    long pbase = ((long)(b * 8 + h)) * 64 * 196;
    float acc[4][4] = {};
    for (int k0 = 0; k0 < 196; k0 += 14) {
        for (int e = t; e < 64 * 14; e += 256) {
            int m = e / 14, kk = e - m * 14;
            Ps[m][kk] = P[pbase + (long)m * 196 + k0 + kk];
        }
        __syncthreads();
#pragma unroll
        for (int kk = 0; kk < 14; ++kk) {
            float a0 = Ps[(ty << 2) + 0][kk];
            float a1 = Ps[(ty << 2) + 1][kk];
            float a2 = Ps[(ty << 2) + 2][kk];
            float a3 = Ps[(ty << 2) + 3][kk];
            float4 bv = *(const float4*)&Vs[k0 + kk][tx << 2];
            acc[0][0] += a0 * bv.x; acc[0][1] += a0 * bv.y; acc[0][2] += a0 * bv.z; acc[0][3] += a0 * bv.w;
            acc[1][0] += a1 * bv.x; acc[1][1] += a1 * bv.y; acc[1][2] += a1 * bv.z; acc[1][3] += a1 * bv.w;
            acc[2][0] += a2 * bv.x; acc[2][1] += a2 * bv.y; acc[2][2] += a2 * bv.z; acc[2][3] += a2 * bv.w;
            acc[3][0] += a3 * bv.x; acc[3][1] += a3 * bv.y; acc[3][2] += a3 * bv.z; acc[3][3] += a3 * bv.w;
        }
        __syncthreads();
    }
    long obase = ((long)b * 64) * 512 + h * 64;
#pragma unroll
    for (int i = 0; i < 4; ++i) {
        long row = obase + (long)((ty << 2) + i) * 512 + (tx << 2);
        o[row + 0] = f2b(acc[i][0]);
        o[row + 1] = f2b(acc[i][1]);
        o[row + 2] = f2b(acc[i][2]);
        o[row + 3] = f2b(acc[i][3]);
    }
}

// ---------------------------------------------------------------------------
// Row softmax over VOCAB=10000
// ---------------------------------------------------------------------------
__global__ __launch_bounds__(256) void softmax_rows(float* __restrict__ out)
{
    __shared__ float red[8];
    long row = blockIdx.x;
    float* p = out + row * 10000L;
    int t = threadIdx.x;
    int w = t >> 6, lane = t & 63;
    float vals[40];
    float mx = -INFINITY;
#pragma unroll
    for (int ii = 0; ii < 40; ++ii) {
        int c = t + (ii << 8);
        if (c < 10000) { float v = p[c]; vals[ii] = v; mx = fmaxf(mx, v); }
        else vals[ii] = -INFINITY;
    }
    for (int off = 32; off; off >>= 1) mx = fmaxf(mx, __shfl_xor(mx, off));
    if (lane == 0) red[w] = mx;
    __syncthreads();
    mx = fmaxf(fmaxf(red[0], red[1]), fmaxf(red[2], red[3]));
    float s = 0.f;
#pragma unroll
    for (int ii = 0; ii < 40; ++ii) {
        float e = __expf(vals[ii] - mx);
        vals[ii] = e;
        s += e;
    }
    for (int off = 32; off; off >>= 1) s += __shfl_xor(s, off);
    if (lane == 0) red[4 + w] = s;
    __syncthreads();
    s = red[4] + red[5] + red[6] + red[7];
    float inv = 1.0f / s;
#pragma unroll
    for (int ii = 0; ii < 40; ++ii) {
        int c = t + (ii << 8);
        if (c < 10000) p[c] = vals[ii] * inv;
    }
}

// ---------------------------------------------------------------------------
extern "C" void kernel_launch(void* const* d_in, const int* in_sizes, int n_in,
                              void* d_out, int out_size, void* d_ws, size_t ws_size,
                              hipStream_t stream)
{
    const int*   x    = (const int*)d_in[0];
    const float* Kin  = (const float*)d_in[1];
    const float* Vin  = (const float*)d_in[2];
    const float* g    = (const float*)d_in[3];
    const float* emb  = (const float*)d_in[5];
    const float* Wq_s = (const float*)d_in[6];
    const float* Wk_s = (const float*)d_in[7];
    const float* Wv_s = (const float*)d_in[8];
    const float* Wo_s = (const float*)d_in[9];
    const float* Wq_c = (const float*)d_in[10];
    const float* Wg_c = (const float*)d_in[11];
    const float* Wk_c = (const float*)d_in[12];
    const float* Wv_c = (const float*)d_in[13];
    const float* Wo_c = (const float*)d_in[14];
    const float* Wf   = (const float*)d_in[15];
    const float* bf   = (const float*)d_in[16];
    float* out = (float*)d_out;
    float* ws  = (float*)d_ws;

    // fp32 region (floats)
    float* qkv = ws;                      // 3 x [2048,512] (q,k,v; q reused as qc)
    float* kc  = qkv + 3 * 1048576;       // [6272,512]
    float* vc  = kc + 3211264;            // [6272,512]
    float* gq  = vc + 3211264;            // [6,32,512]
    float* P   = gq + 98304;              // [32,8,64,196]
    // bf16 region (ushort), after fp32 region
    ushort_t* act_bf   = (ushort_t*)(P + 3211264);     // [2048,512]
    ushort_t* attno_bf = act_bf + 1048576;             // [2048,512]
    ushort_t* K_bf     = attno_bf + 1048576;           // [32,196,512]
    ushort_t* V_bf     = K_bf + 3211264;               // [32,196,512]
    ushort_t* W8t      = V_bf + 3211264;               // 8 mats x 6 layers x [512,512]^T
    ushort_t* Wf_t     = W8t + 48L * S2;               // [10112,512] (padded)

    // one-time (per call) weight/input conversions
    convw_t<<<dim3(8, 8, 48), 256, 0, stream>>>(Wq_s, Wk_s, Wv_s, Wo_s,
                                                Wq_c, Wk_c, Wv_c, Wo_c, W8t);
    convwf_t<<<dim3(158, 8), 256, 0, stream>>>(Wf, Wf_t);
    conv2<<<dim3(3136, 2), 256, 0, stream>>>(Kin, Vin, K_bf, V_bf);
    embed_pe<<<4096, 256, 0, stream>>>(x, emb, act_bf);
    gemm_k<<<dim3(8, 1, 6), 256, 0, stream>>>(g, Wg_c, (long)S2, gq, 16384L, 32, 512, 512);

    const ushort_t* Wq_s_t = W8t + 0L * 6 * S2;
    const ushort_t* Wk_s_t = W8t + 1L * 6 * S2;
    const ushort_t* Wv_s_t = W8t + 2L * 6 * S2;
    const ushort_t* Wo_s_t = W8t + 3L * 6 * S2;
    const ushort_t* Wq_c_t = W8t + 4L * 6 * S2;
    const ushort_t* Wk_c_t = W8t + 5L * 6 * S2;
    const ushort_t* Wv_c_t = W8t + 6L * 6 * S2;
    const ushort_t* Wo_c_t = W8t + 7L * 6 * S2;

    for (int l = 0; l < 6; ++l) {
        long wo = (long)l * S2;
        // q,k,v projections (fp32 out for attention)
        gemm_bt<<<dim3(4, 16, 3), 256, 0, stream>>>(
            act_bf, act_bf, act_bf, Wq_s_t + wo, Wk_s_t + wo, Wv_s_t + wo, 0L,
            qkv, 1048576L, (ushort_t*)nullptr, 0L, 2048, 512, 512, 512, nullptr);
        self_attn<<<256, 256, 0, stream>>>(qkv, qkv + 1048576, qkv + 2097152, attno_bf);
        // out = attn @ Wo_s  (bf16 out -> act)
        gemm_bt<<<dim3(4, 16, 1), 256, 0, stream>>>(
            attno_bf, attno_bf, attno_bf, Wo_s_t + wo, Wo_s_t + wo, Wo_s_t + wo, 0L,
            (float*)nullptr, 0L, act_bf, 0L, 2048, 512, 512, 512, nullptr);
        // kc, vc projections (fp32 out)
        gemm_bt<<<dim3(4, 49, 2), 256, 0, stream>>>(
            K_bf, V_bf, V_bf, Wk_c_t + wo, Wv_c_t + wo, Wv_c_t + wo, 0L,
            kc, 3211264L, (ushort_t*)nullptr, 0L, 6272, 512, 512, 512, nullptr);
        // qc = act @ Wq_c (fp32 out, reuse qkv buffer)
        gemm_bt<<<dim3(4, 16, 1), 256, 0, stream>>>(
            act_bf, act_bf, act_bf, Wq_c_t + wo, Wq_c_t + wo, Wq_c_t + wo, 0L,
            qkv, 0L, (ushort_t*)nullptr, 0L, 2048, 512, 512, 512, nullptr);
        cross_scores<<<256, 256, 0, stream>>>(qkv, gq + (long)l * 16384, kc, P);
        cross_pv<<<256, 256, 0, stream>>>(P, vc, attno_bf);
        // out = cross @ Wo_c (bf16 out -> act)
        gemm_bt<<<dim3(4, 16, 1), 256, 0, stream>>>(
            attno_bf, attno_bf, attno_bf, Wo_c_t + wo, Wo_c_t + wo, Wo_c_t + wo, 0L,
            (float*)nullptr, 0L, act_bf, 0L, 2048, 512, 512, 512, nullptr);
    }

    // logits (bias) then softmax
    gemm_bt<<<dim3(79, 16, 1), 256, 0, stream>>>(
        act_bf, act_bf, act_bf, Wf_t, Wf_t, Wf_t, 0L,
        out, 0L, (ushort_t*)nullptr, 0L, 2048, 10000, 10112, 512, bf);
    softmax_rows<<<2048, 256, 0, stream>>>(out);
}

// Round 3
// 1135.432 us; speedup vs baseline: 2.4786x; 1.2871x over previous
//
#include <hip/hip_runtime.h>
#include <math.h>

// GlobalAdaptiveDecoder: B=32 S=64 D=512 H=8 DK=DV=64 NR=196 L=6 VOCAB=10000
// Round 3: weight fusion (Wo_s@Wq_c, Wo_c@Wqkv_s), batched kc/vc precompute,
// bf16 logits + bf16 activation flow, LDS-coalesced GEMM epilogues,
// merged prep kernel. Launches 54 -> 38.

#define S2 (512*512)
typedef unsigned short ushort_t;
typedef unsigned int u32;
typedef __attribute__((ext_vector_type(8))) short short8;
typedef __attribute__((ext_vector_type(4))) float f32x4;

__device__ __forceinline__ ushort_t f2b(float f) {
    union { float f; u32 u; } v; v.f = f;
    u32 r = (v.u + 0x7fffu + ((v.u >> 16) & 1u)) >> 16;
    return (ushort_t)r;
}
__device__ __forceinline__ float b2f(ushort_t u) {
    union { u32 u; float f; } v; v.u = ((u32)u) << 16; return v.f;
}
__device__ __forceinline__ void glds16(const void* g, void* l) {
    __builtin_amdgcn_global_load_lds((const __attribute__((address_space(1))) u32*)g,
                                     (__attribute__((address_space(3))) u32*)l,
                                     16, 0, 0);
}

// ---------------------------------------------------------------------------
// bf16 MFMA GEMM, 128x128 tile, BK=32, z-batched: zm=z%amod selects A/B pair,
// zl=z/amod advances A by az and B by bz. C = A @ B^T (+biasc per col), bf16
// out via LDS-coalesced epilogue (uint4 = 8 ushorts per store).
// M mult of 128; B must have gridDim.x*128 valid rows; N mult of 8.
// ---------------------------------------------------------------------------
__global__ __launch_bounds__(256) void gemm_bt(
    const ushort_t* __restrict__ A0, const ushort_t* __restrict__ A1, const ushort_t* __restrict__ A2,
    const ushort_t* __restrict__ B0, const ushort_t* __restrict__ B1, const ushort_t* __restrict__ B2,
    long az, long bz, int amod, ushort_t* __restrict__ C, long cz,
    int M, int N, int K, const float* __restrict__ biasc)
{
    int z = blockIdx.z, zm = z % amod;
    long zl = z / amod;
    const ushort_t* A = ((zm == 0) ? A0 : (zm == 1) ? A1 : A2) + zl * az;
    const ushort_t* B = ((zm == 0) ? B0 : (zm == 1) ? B1 : B2) + zl * bz;
    ushort_t* Cp = C + (long)z * cz;

    int m0 = blockIdx.y * 128, n0 = blockIdx.x * 128;
    __shared__ ushort_t As[128 * 32];
    __shared__ ushort_t Bs[128 * 32];
    __shared__ __align__(16) ushort_t Cs[4][16 * 80];
    int t = threadIdx.x;
    int sr = t >> 2, sk = (t & 3) * 8;
    int wv = t >> 6, lane = t & 63;
    int wr = (wv >> 1) * 64, wc = (wv & 1) * 64;
    int lr = lane & 15, lq = lane >> 4;

    f32x4 acc[4][4];
#pragma unroll
    for (int i = 0; i < 4; ++i)
#pragma unroll
        for (int j = 0; j < 4; ++j) acc[i][j] = (f32x4){0.f, 0.f, 0.f, 0.f};

    for (int k0 = 0; k0 < K; k0 += 32) {
        glds16(A + (long)(m0 + sr) * K + k0 + sk,      (void*)(As + t * 8));
        glds16(A + (long)(m0 + sr + 64) * K + k0 + sk, (void*)(As + (t + 256) * 8));
        glds16(B + (long)(n0 + sr) * K + k0 + sk,      (void*)(Bs + t * 8));
        glds16(B + (long)(n0 + sr + 64) * K + k0 + sk, (void*)(Bs + (t + 256) * 8));
        __syncthreads();
        short8 af[4], bfr[4];
#pragma unroll
        for (int i = 0; i < 4; ++i)
            af[i] = *(const short8*)&As[(wr + i * 16 + lr) * 32 + lq * 8];
#pragma unroll
        for (int j = 0; j < 4; ++j)
            bfr[j] = *(const short8*)&Bs[(wc + j * 16 + lr) * 32 + lq * 8];
#pragma unroll
        for (int i = 0; i < 4; ++i)
#pragma unroll
            for (int j = 0; j < 4; ++j)
                acc[i][j] = __builtin_amdgcn_mfma_f32_16x16x32_bf16(af[i], bfr[j], acc[i][j], 0, 0, 0);
        __syncthreads();
    }

    // LDS-coalesced epilogue, one 16x64 strip per wave per i
#pragma unroll
    for (int i = 0; i < 4; ++i) {
#pragma unroll
        for (int j = 0; j < 4; ++j) {
            int colg = n0 + wc + j * 16 + lr;
            float bb = (biasc && colg < N) ? biasc[colg] : 0.f;
#pragma unroll
            for (int r = 0; r < 4; ++r)
                Cs[wv][(lq * 4 + r) * 80 + j * 16 + lr] = f2b(acc[i][j][r] + bb);
        }
        __syncthreads();
#pragma unroll
        for (int rr = 0; rr < 2; ++rr) {
            int c = lane + 64 * rr;
            int row = c >> 3, g8 = c & 7;
            uint4 u = *(const uint4*)&Cs[wv][row * 80 + g8 * 8];
            int colg = n0 + wc + g8 * 8;
            int rowg = m0 + wr + i * 16 + row;
            if (colg < N) *(uint4*)&Cp[(long)rowg * N + colg] = u;
        }
        __syncthreads();
    }
}

// ---------------------------------------------------------------------------
// bf16 MFMA GEMM, 64x64 tile (256 blocks for M=2048,N=512 -> full occupancy).
// Optional bias2[(row>>6)*512 + col] added pre-rounding (gq for qc GEMM).
// ---------------------------------------------------------------------------
__global__ __launch_bounds__(256) void gemm_bt64(
    const ushort_t* __restrict__ A, const ushort_t* __restrict__ B,
    ushort_t* __restrict__ C, int M, int N, int K, const float* __restrict__ bias2)
{
    int m0 = blockIdx.y * 64, n0 = blockIdx.x * 64;
    __shared__ ushort_t As[64 * 32];
    __shared__ ushort_t Bs[64 * 32];
    int t = threadIdx.x;
    int sr = t >> 2, sk = (t & 3) * 8;
    int wv = t >> 6, lane = t & 63;
    int wr = (wv >> 1) * 32, wc = (wv & 1) * 32;
    int lr = lane & 15, lq = lane >> 4;

    f32x4 acc[2][2];
#pragma unroll
    for (int i = 0; i < 2; ++i)
#pragma unroll
        for (int j = 0; j < 2; ++j) acc[i][j] = (f32x4){0.f, 0.f, 0.f, 0.f};

    for (int k0 = 0; k0 < K; k0 += 32) {
        glds16(A + (long)(m0 + sr) * K + k0 + sk, (void*)(As + t * 8));
        glds16(B + (long)(n0 + sr) * K + k0 + sk, (void*)(Bs + t * 8));
        __syncthreads();
        short8 af[2], bfr[2];
#pragma unroll
        for (int i = 0; i < 2; ++i)
            af[i] = *(const short8*)&As[(wr + i * 16 + lr) * 32 + lq * 8];
#pragma unroll
        for (int j = 0; j < 2; ++j)
            bfr[j] = *(const short8*)&Bs[(wc + j * 16 + lr) * 32 + lq * 8];
#pragma unroll
        for (int i = 0; i < 2; ++i)
#pragma unroll
            for (int j = 0; j < 2; ++j)
                acc[i][j] = __builtin_amdgcn_mfma_f32_16x16x32_bf16(af[i], bfr[j], acc[i][j], 0, 0, 0);
        __syncthreads();
    }

#pragma unroll
    for (int i = 0; i < 2; ++i)
#pragma unroll
        for (int j = 0; j < 2; ++j) {
            int colg = n0 + wc + j * 16 + lr;
#pragma unroll
            for (int r = 0; r < 4; ++r) {
                int rowg = m0 + wr + i * 16 + lq * 4 + r;
                float v = acc[i][j][r];
                if (bias2) v += bias2[(rowg >> 6) * 512 + colg];
                C[(long)rowg * N + colg] = f2b(v);
            }
        }
}

// ---------------------------------------------------------------------------
// fp32 GEMM for gq = g @ Wg_c (M=32, tiny). 64x64 tile, BK=16, z over layers.
// ---------------------------------------------------------------------------
#define BKk 16
__global__ __launch_bounds__(256) void gemm_k(
    const float* __restrict__ Ain, const float* __restrict__ Bin,
    long bz, float* __restrict__ Cout, long cz, int M, int N, int K)
{
    int z = blockIdx.z;
    const float* A = Ain;
    const float* B = Bin + (long)z * bz;
    float* Cp = Cout + (long)z * cz;
    int n0 = blockIdx.x * 64, m0 = blockIdx.y * 64;
    __shared__ float As[BKk][68];
    __shared__ float Bs[BKk][68];
    int t = threadIdx.x;
    int tx = t & 15, ty = t >> 4;
    int am = t >> 2, ak = (t & 3) << 2;
    int bk = t >> 4, bn = (t & 15) << 2;
    float acc[4][4] = {};
    const bool amok = (m0 + am) < M;

    for (int k0 = 0; k0 < K; k0 += BKk) {
        float4 av = make_float4(0.f, 0.f, 0.f, 0.f);
        if (amok) av = *(const float4*)(A + (long)(m0 + am) * K + (k0 + ak));
        float4 bv = *(const float4*)(B + (long)(k0 + bk) * N + (n0 + bn));
        __syncthreads();
        As[ak + 0][am] = av.x; As[ak + 1][am] = av.y;
        As[ak + 2][am] = av.z; As[ak + 3][am] = av.w;
        *(float4*)&Bs[bk][bn] = bv;
        __syncthreads();
#pragma unroll
        for (int kk = 0; kk < BKk; ++kk) {
            float4 a = *(const float4*)&As[kk][ty << 2];
            float4 b = *(const float4*)&Bs[kk][tx << 2];
            acc[0][0] += a.x * b.x; acc[0][1] += a.x * b.y; acc[0][2] += a.x * b.z; acc[0][3] += a.x * b.w;
            acc[1][0] += a.y * b.x; acc[1][1] += a.y * b.y; acc[1][2] += a.y * b.z; acc[1][3] += a.y * b.w;
            acc[2][0] += a.z * b.x; acc[2][1] += a.z * b.y; acc[2][2] += a.z * b.z; acc[2][3] += a.z * b.w;
            acc[3][0] += a.w * b.x; acc[3][1] += a.w * b.y; acc[3][2] += a.w * b.z; acc[3][3] += a.w * b.w;
        }
    }
#pragma unroll
    for (int i = 0; i < 4; ++i) {
        int m = m0 + (ty << 2) + i;
        if (m >= M) break;
        *(float4*)(Cp + (long)m * N + n0 + (tx << 2)) =
            make_float4(acc[i][0], acc[i][1], acc[i][2], acc[i][3]);
    }
}

// ---------------------------------------------------------------------------
// Merged prep: zone1 transpose 48 weight mats -> bf16^T; zone2 Wf -> [10112,512]
// bf16^T (padded); zone3 plain bf16 of Wo_s/Wo_c; zone4 Kin/Vin -> bf16;
// zone5 embed+PE -> bf16 act0. One launch, 17776 blocks.
// ---------------------------------------------------------------------------
__global__ __launch_bounds__(256) void prep(
    const int* __restrict__ x, const float* __restrict__ emb,
    const float* __restrict__ Wq_s, const float* __restrict__ Wk_s,
    const float* __restrict__ Wv_s, const float* __restrict__ Wo_s,
    const float* __restrict__ Wq_c, const float* __restrict__ Wk_c,
    const float* __restrict__ Wv_c, const float* __restrict__ Wo_c,
    const float* __restrict__ Wf, const float* __restrict__ Kin, const float* __restrict__ Vin,
    ushort_t* __restrict__ W8t, ushort_t* __restrict__ Wf_t,
    ushort_t* __restrict__ Wo_sp, ushort_t* __restrict__ Wo_cp,
    ushort_t* __restrict__ K_bf, ushort_t* __restrict__ V_bf, ushort_t* __restrict__ act0)
{
    __shared__ float tile[64][65];
    int bid = blockIdx.x, t = threadIdx.x;
    if (bid < 3072) {                       // zone1: 48 mats x 64 tile-blocks
        int mat = bid >> 6, wsel = mat / 6, l = mat % 6;
        const float* src = (wsel == 0) ? Wq_s : (wsel == 1) ? Wk_s : (wsel == 2) ? Wv_s :
                           (wsel == 3) ? Wo_s : (wsel == 4) ? Wq_c : (wsel == 5) ? Wk_c :
                           (wsel == 6) ? Wv_c : Wo_c;
        src += (long)l * S2;
        ushort_t* dst = W8t + (long)mat * S2;
        int within = bid & 63;
        int n0 = (within & 7) * 64, k0 = (within >> 3) * 64;
        for (int e = t; e < 4096; e += 256) {
            int r = e >> 6, c = e & 63;
            tile[r][c] = src[(long)(k0 + r) * 512 + n0 + c];
        }
        __syncthreads();
        for (int e = t; e < 4096; e += 256) {
            int r = e >> 6, c = e & 63;
            dst[(long)(n0 + r) * 512 + k0 + c] = f2b(tile[c][r]);
        }
    } else if (bid < 4336) {                // zone2: Wf transpose, 158 x 8 blocks
        int id = bid - 3072;
        int n0 = (id % 158) * 64, k0 = (id / 158) * 64;
        for (int e = t; e < 4096; e += 256) {
            int r = e >> 6, c = e & 63;
            int n = n0 + c;
            tile[r][c] = (n < 10000) ? Wf[(long)(k0 + r) * 10000 + n] : 0.f;
        }
        __syncthreads();
        for (int e = t; e < 4096; e += 256) {
            int r = e >> 6, c = e & 63;
            Wf_t[(long)(n0 + r) * 512 + k0 + c] = f2b(tile[c][r]);
        }
    } else if (bid < 7408) {                // zone3: plain Wo_s / Wo_c bf16
        long i = (long)(bid - 4336) * 1024 + t * 4;
        const float* s; ushort_t* o; long off;
        if (i < 6L * S2) { s = Wo_s; o = Wo_sp; off = i; }
        else             { s = Wo_c; o = Wo_cp; off = i - 6L * S2; }
        float4 v = *(const float4*)(s + off);
        ushort4 u; u.x = f2b(v.x); u.y = f2b(v.y); u.z = f2b(v.z); u.w = f2b(v.w);
        *(ushort4*)(o + off) = u;
    } else if (bid < 13680) {               // zone4: Kin/Vin -> bf16
        long i = (long)(bid - 7408) * 1024 + t * 4;
        const float* s; ushort_t* o; long off;
        if (i < 3211264L) { s = Kin; o = K_bf; off = i; }
        else              { s = Vin; o = V_bf; off = i - 3211264L; }
        float4 v = *(const float4*)(s + off);
        ushort4 u; u.x = f2b(v.x); u.y = f2b(v.y); u.z = f2b(v.z); u.w = f2b(v.w);
        *(ushort4*)(o + off) = u;
    } else {                                // zone5: embed + PE
        long i = (long)(bid - 13680) * 256 + t;
        int d = (int)(i & 511);
        long tok = i >> 9;
        int s = (int)(tok & 63);
        int id = x[tok];
        int j = d >> 1;
        double ang = (double)s * exp(-log(10000.0) * (2.0 * j) / 512.0);
        float pe = (d & 1) ? (float)cos(ang) : (float)sin(ang);
        act0[i] = f2b(emb[(long)id * 512 + d] + pe);
    }
}

// ---------------------------------------------------------------------------
// Fused causal self-attention (fp32 math, bf16 in/out). Block per (b,h).
// ---------------------------------------------------------------------------
__global__ __launch_bounds__(256) void self_attn(const ushort_t* __restrict__ q,
                                                 const ushort_t* __restrict__ k,
                                                 const ushort_t* __restrict__ v,
                                                 ushort_t* __restrict__ o)
{
    int b = blockIdx.x >> 3, h = blockIdx.x & 7;
    __shared__ float Ks[64][68], Vs[64][68], Qs[64][68];
    int t = threadIdx.x;
    long base = ((long)b * 64) * 512 + h * 64;
    for (int e = t; e < 4096; e += 256) {
        int r = e >> 6, c = e & 63;
        long gidx = base + (long)r * 512 + c;
        Ks[r][c] = b2f(k[gidx]);
        Vs[r][c] = b2f(v[gidx]);
        Qs[r][c] = b2f(q[gidx]);
    }
    __syncthreads();
    int w = t >> 6, lane = t & 63;

    for (int g4 = 0; g4 < 4; ++g4) {
        int qi0 = w * 16 + g4 * 4;
        float s[4] = {0.f, 0.f, 0.f, 0.f};
#pragma unroll
        for (int d4 = 0; d4 < 16; ++d4) {
            float4 kv = *(const float4*)&Ks[lane][d4 << 2];
#pragma unroll
            for (int r = 0; r < 4; ++r) {
                float4 qv = *(const float4*)&Qs[qi0 + r][d4 << 2];
                s[r] += qv.x * kv.x + qv.y * kv.y + qv.z * kv.z + qv.w * kv.w;
            }
        }
#pragma unroll
        for (int r = 0; r < 4; ++r) {
            int qi = qi0 + r;
            float sv = (lane <= qi) ? s[r] * 0.125f : -INFINITY;
            float m = sv;
            for (int off = 32; off; off >>= 1) m = fmaxf(m, __shfl_xor(m, off));
            float p = __expf(sv - m);
            float sum = p;
            for (int off = 32; off; off >>= 1) sum += __shfl_xor(sum, off);
            Qs[qi][lane] = p / sum;
        }
    }
    __syncthreads();

#pragma unroll
    for (int gg = 0; gg < 2; ++gg) {
        int qi0 = w * 16 + gg * 8;
        float acc[8] = {};
        for (int j = 0; j < 64; ++j) {
            float vv = Vs[j][lane];
#pragma unroll
            for (int r = 0; r < 8; ++r) acc[r] += Qs[qi0 + r][j] * vv;
        }
#pragma unroll
        for (int r = 0; r < 8; ++r)
            o[base + (long)(qi0 + r) * 512 + lane] = f2b(acc[r]);
    }
}

// ---------------------------------------------------------------------------
// Cross-attn part 1: P = softmax(qc Kc^T / 8). qc already includes gq bias.
// ---------------------------------------------------------------------------
__global__ __launch_bounds__(256) void cross_scores(const ushort_t* __restrict__ qc,
                                                    const ushort_t* __restrict__ kc,
                                                    float* __restrict__ P)
{
    int b = blockIdx.x >> 3, h = blockIdx.x & 7;
    __shared__ float Ks[196][68];
    __shared__ float qv[4][68];
    __shared__ float red[2][4][4];
    int t = threadIdx.x;
    long kbase = ((long)b * 196) * 512 + h * 64;
    for (int e = t; e < 196 * 64; e += 256) {
        int r = e >> 6, c = e & 63;
        Ks[r][c] = b2f(kc[kbase + (long)r * 512 + c]);
    }
    int w = t >> 6, lane = t & 63;
    long qbase = ((long)b * 64) * 512 + h * 64;
    long pbase = ((long)(b * 8 + h)) * 64 * 196;
    __syncthreads();

    for (int qb = 0; qb < 16; ++qb) {
        qv[w][lane] = b2f(qc[qbase + (long)(qb * 4 + w) * 512 + lane]);
        __syncthreads();
        float s[4];
        if (t < 196) {
            s[0] = s[1] = s[2] = s[3] = 0.f;
#pragma unroll
            for (int d4 = 0; d4 < 16; ++d4) {
                float4 kvv = *(const float4*)&Ks[t][d4 << 2];
#pragma unroll
                for (int r = 0; r < 4; ++r) {
                    float4 qf = *(const float4*)&qv[r][d4 << 2];
                    s[r] += qf.x * kvv.x + qf.y * kvv.y + qf.z * kvv.z + qf.w * kvv.w;
                }
            }
#pragma unroll
            for (int r = 0; r < 4; ++r) s[r] *= 0.125f;
        } else {
            s[0] = s[1] = s[2] = s[3] = -INFINITY;
        }
        float m[4], p[4], su[4];
#pragma unroll
        for (int r = 0; r < 4; ++r) {
            m[r] = s[r];
            for (int off = 32; off; off >>= 1) m[r] = fmaxf(m[r], __shfl_xor(m[r], off));
        }
        if (lane == 0) { for (int r = 0; r < 4; ++r) red[0][w][r] = m[r]; }
        __syncthreads();
#pragma unroll
        for (int r = 0; r < 4; ++r) {
            float mm = fmaxf(fmaxf(red[0][0][r], red[0][1][r]), fmaxf(red[0][2][r], red[0][3][r]));
            p[r] = (t < 196) ? __expf(s[r] - mm) : 0.f;
            su[r] = p[r];
            for (int off = 32; off; off >>= 1) su[r] += __shfl_xor(su[r], off);
        }
        if (lane == 0) { for (int r = 0; r < 4; ++r) red[1][w][r] = su[r]; }
        __syncthreads();
        if (t < 196) {
#pragma unroll
            for (int r = 0; r < 4; ++r) {
                float tot = red[1][0][r] + red[1][1][r] + red[1][2][r] + red[1][3][r];
                P[pbase + (long)(qb * 4 + r) * 196 + t] = p[r] / tot;
            }
        }
        __syncthreads();
    }
}

// ---------------------------------------------------------------------------
// Cross-attn part 2: O = P @ Vc -> bf16. Block per (b,h).
// ---------------------------------------------------------------------------
__global__ __launch_bounds__(256) void cross_pv(const float* __restrict__ P,
                                                const ushort_t* __restrict__ vc,
                                                ushort_t* __restrict__ o)
{
    int b = blockIdx.x >> 3, h = blockIdx.x & 7;
    __shared__ float Vs[196][68];
    __shared__ float Ps[64][18];
    int t = threadIdx.x;
    int tx = t & 15, ty = t >> 4;
    long vbase = ((long)b * 196) * 512 + h * 64;
    for (int e = t; e < 196 * 64; e += 256) {
        int r = e >> 6, c = e & 63;
        Vs[r][c] = b2f(vc[vbase + (long)r * 512 + c]);
    }
    long pbase = ((long)(b * 8 + h)) * 64 * 196;
    float acc[4][4] = {};
    for (int k0 = 0; k0 < 196; k0 += 14) {
        for (int e = t; e < 64 * 14; e += 256) {
            int m = e / 14, kk = e - m * 14;
            Ps[m][kk] = P[pbase + (long)m * 196 + k0 + kk];
        }
        __syncthreads();
#pragma unroll
        for (int kk = 0; kk < 14; ++kk) {
            float a0 = Ps[(ty << 2) + 0][kk];
            float a1 = Ps[(ty << 2) + 1][kk];
            float a2 = Ps[(ty << 2) + 2][kk];
            float a3 = Ps[(ty << 2) + 3][kk];
            float4 bv = *(const float4*)&Vs[k0 + kk][tx << 2];
            acc[0][0] += a0 * bv.x; acc[0][1] += a0 * bv.y; acc[0][2] += a0 * bv.z; acc[0][3] += a0 * bv.w;
            acc[1][0] += a1 * bv.x; acc[1][1] += a1 * bv.y; acc[1][2] += a1 * bv.z; acc[1][3] += a1 * bv.w;
            acc[2][0] += a2 * bv.x; acc[2][1] += a2 * bv.y; acc[2][2] += a2 * bv.z; acc[2][3] += a2 * bv.w;
            acc[3][0] += a3 * bv.x; acc[3][1] += a3 * bv.y; acc[3][2] += a3 * bv.z; acc[3][3] += a3 * bv.w;
        }
        __syncthreads();
    }
    long obase = ((long)b * 64) * 512 + h * 64;
#pragma unroll
    for (int i = 0; i < 4; ++i) {
        long row = obase + (long)((ty << 2) + i) * 512 + (tx << 2);
        o[row + 0] = f2b(acc[i][0]);
        o[row + 1] = f2b(acc[i][1]);
        o[row + 2] = f2b(acc[i][2]);
        o[row + 3] = f2b(acc[i][3]);
    }
}

// ---------------------------------------------------------------------------
// Softmax over bf16 logits -> fp32 probs. One block per row.
// ---------------------------------------------------------------------------
__global__ __launch_bounds__(256) void softmax_bf(const ushort_t* __restrict__ lg,
                                                  float* __restrict__ out)
{
    __shared__ float red[8];
    long row = blockIdx.x;
    const ushort_t* p = lg + row * 10000L;
    float* po = out + row * 10000L;
    int t = threadIdx.x;
    int w = t >> 6, lane = t & 63;
    float vals[40];
    float mx = -INFINITY;
#pragma unroll
    for (int ii = 0; ii < 40; ++ii) {
        int c = t + (ii << 8);
        if (c < 10000) { float v = b2f(p[c]); vals[ii] = v; mx = fmaxf(mx, v); }
        else vals[ii] = -INFINITY;
    }
    for (int off = 32; off; off >>= 1) mx = fmaxf(mx, __shfl_xor(mx, off));
    if (lane == 0) red[w] = mx;
    __syncthreads();
    mx = fmaxf(fmaxf(red[0], red[1]), fmaxf(red[2], red[3]));
    float s = 0.f;
#pragma unroll
    for (int ii = 0; ii < 40; ++ii) {
        float e = __expf(vals[ii] - mx);
        vals[ii] = e;
        s += e;
    }
    for (int off = 32; off; off >>= 1) s += __shfl_xor(s, off);
    if (lane == 0) red[4 + w] = s;
    __syncthreads();
    s = red[4] + red[5] + red[6] + red[7];
    float inv = 1.0f / s;
#pragma unroll
    for (int ii = 0; ii < 40; ++ii) {
        int c = t + (ii << 8);
        if (c < 10000) po[c] = vals[ii] * inv;
    }
}

// ---------------------------------------------------------------------------
extern "C" void kernel_launch(void* const* d_in, const int* in_sizes, int n_in,
                              void* d_out, int out_size, void* d_ws, size_t ws_size,
                              hipStream_t stream)
{
    const int*   x    = (const int*)d_in[0];
    const float* Kin  = (const float*)d_in[1];
    const float* Vin  = (const float*)d_in[2];
    const float* g    = (const float*)d_in[3];
    const float* emb  = (const float*)d_in[5];
    const float* Wq_s = (const float*)d_in[6];
    const float* Wk_s = (const float*)d_in[7];
    const float* Wv_s = (const float*)d_in[8];
    const float* Wo_s = (const float*)d_in[9];
    const float* Wq_c = (const float*)d_in[10];
    const float* Wg_c = (const float*)d_in[11];
    const float* Wk_c = (const float*)d_in[12];
    const float* Wv_c = (const float*)d_in[13];
    const float* Wo_c = (const float*)d_in[14];
    const float* Wf   = (const float*)d_in[15];
    const float* bf   = (const float*)d_in[16];
    float* out = (float*)d_out;

    // workspace layout
    float* gq = (float*)d_ws;                               // [6,32,512]
    float* P  = gq + 98304;                                  // [32,8,64,196]
    ushort_t* base     = (ushort_t*)(P + 3211264);
    ushort_t* act0     = base;                               // [2048,512]
    ushort_t* qkv_bf   = act0 + 1048576;                     // 3 x [2048,512]
    ushort_t* attnout  = qkv_bf + 3145728;                   // [2048,512]
    ushort_t* qc_bf    = attnout + 1048576;                  // [2048,512]
    ushort_t* crossout = qc_bf + 1048576;                    // [2048,512]
    ushort_t* K_bf     = crossout + 1048576;                 // [6272,512]
    ushort_t* V_bf     = K_bf + 3211264;                     // [6272,512]
    ushort_t* kcvc     = V_bf + 3211264;                     // 12 x [6272,512]
    ushort_t* W8t      = kcvc + 12L * 3211264;               // 48 x [512,512]^T
    ushort_t* Wf_t     = W8t + 48L * S2;                     // [10112,512]
    ushort_t* Wo_sp    = Wf_t + 5177344;                     // 6 x [512,512] plain
    ushort_t* Wo_cp    = Wo_sp + 6L * S2;                    // 6 x [512,512] plain
    ushort_t* Fqc_t    = Wo_cp + 6L * S2;                    // 6 x [512,512]
    ushort_t* Fqkv_t   = Fqc_t + 6L * S2;                    // 15 x [512,512]
    ushort_t* logits   = kcvc;                               // reuse (kcvc done by then)

    const ushort_t* Wq_s_t = W8t + 0L  * 6 * S2;
    const ushort_t* Wk_s_t = W8t + 1L  * 6 * S2;
    const ushort_t* Wv_s_t = W8t + 2L  * 6 * S2;
    const ushort_t* Wq_c_t = W8t + 4L  * 6 * S2;
    const ushort_t* Wk_c_t = W8t + 5L  * 6 * S2;
    const ushort_t* Wv_c_t = W8t + 6L  * 6 * S2;
    const ushort_t* Wo_c_t = W8t + 7L  * 6 * S2;

    // setup: conversions + gq + fused weight products + kc/vc (all layers)
    prep<<<17776, 256, 0, stream>>>(x, emb, Wq_s, Wk_s, Wv_s, Wo_s, Wq_c, Wk_c, Wv_c, Wo_c,
                                    Wf, Kin, Vin, W8t, Wf_t, Wo_sp, Wo_cp, K_bf, V_bf, act0);
    gemm_k<<<dim3(8, 1, 6), 256, 0, stream>>>(g, Wg_c, (long)S2, gq, 16384L, 32, 512, 512);
    // Fqc_t[l] = (Wo_s[l] @ Wq_c[l])^T = Wq_c_t[l] @ Wo_s[l]^T(plain)
    gemm_bt<<<dim3(4, 4, 6), 256, 0, stream>>>(
        Wq_c_t, Wq_c_t + S2, Wq_c_t + 2 * S2, Wo_sp, Wo_sp + S2, Wo_sp + 2 * S2,
        3L * S2, 3L * S2, 3, Fqc_t, (long)S2, 512, 512, 512, nullptr);
    // Fqkv_t[l][m] = (Wo_c[l] @ W{m}_s[l+1])^T = W{m}_s_t[l+1] @ Wo_c[l]^T(plain)
    gemm_bt<<<dim3(4, 4, 15), 256, 0, stream>>>(
        Wq_s_t + S2, Wk_s_t + S2, Wv_s_t + S2, Wo_cp, Wo_cp, Wo_cp,
        (long)S2, (long)S2, 3, Fqkv_t, (long)S2, 512, 512, 512, nullptr);
    // kc/vc for all 6 layers: z = l*2 + {0:K,1:V}
    gemm_bt<<<dim3(4, 49, 12), 256, 0, stream>>>(
        K_bf, V_bf, V_bf, Wk_c_t, Wv_c_t, Wv_c_t,
        0L, (long)S2, 2, kcvc, 3211264L, 6272, 512, 512, nullptr);

    for (int l = 0; l < 6; ++l) {
        const ushort_t *Bq, *Bk, *Bv, *A;
        if (l == 0) { A = act0; Bq = Wq_s_t; Bk = Wk_s_t; Bv = Wv_s_t; }
        else {
            A = crossout;
            Bq = Fqkv_t + (long)((l - 1) * 3) * S2;
            Bk = Bq + S2; Bv = Bq + 2 * S2;
        }
        gemm_bt<<<dim3(4, 16, 3), 256, 0, stream>>>(
            A, A, A, Bq, Bk, Bv, 0L, 0L, 3, qkv_bf, 1048576L, 2048, 512, 512, nullptr);
        self_attn<<<256, 256, 0, stream>>>(qkv_bf, qkv_bf + 1048576, qkv_bf + 2097152, attnout);
        gemm_bt64<<<dim3(8, 32), 256, 0, stream>>>(
            attnout, Fqc_t + (long)l * S2, qc_bf, 2048, 512, 512, gq + (long)l * 16384);
        cross_scores<<<256, 256, 0, stream>>>(qc_bf, kcvc + (long)(2 * l) * 3211264, P);
        cross_pv<<<256, 256, 0, stream>>>(P, kcvc + (long)(2 * l + 1) * 3211264, crossout);
    }

    // final: out5 = crossout @ Wo_c[5]; logits = out5 @ Wf + bf (bf16); softmax
    gemm_bt64<<<dim3(8, 32), 256, 0, stream>>>(
        crossout, Wo_c_t + 5L * S2, act0, 2048, 512, 512, nullptr);
    gemm_bt<<<dim3(79, 16, 1), 256, 0, stream>>>(
        act0, act0, act0, Wf_t, Wf_t, Wf_t, 0L, 0L, 3,
        logits, 0L, 2048, 10000, 512, bf);
    softmax_bf<<<2048, 256, 0, stream>>>(logits, out);
}

// Round 4
// 744.367 us; speedup vs baseline: 3.7808x; 1.5254x over previous
//
#include <hip/hip_runtime.h>
#include <math.h>

// GlobalAdaptiveDecoder: B=32 S=64 D=512 H=8 DK=DV=64 NR=196 L=6 VOCAB=10000
// Round 4: fully-fused per-layer kernels (layer_self, layer_cross) at 256
// blocks = 1 block/CU; kc/vc computed in-kernel (removes 150+ MB HBM traffic);
// Wfin = Wo_c[5]@Wf pre-fused; 17 launches total.

#define S2 (512*512)
typedef unsigned short ushort_t;
typedef unsigned int u32;
typedef __attribute__((ext_vector_type(8))) short short8;
typedef __attribute__((ext_vector_type(4))) float f32x4;

__device__ __forceinline__ ushort_t f2b(float f) {
    union { float f; u32 u; } v; v.f = f;
    u32 r = (v.u + 0x7fffu + ((v.u >> 16) & 1u)) >> 16;
    return (ushort_t)r;
}
__device__ __forceinline__ float b2f(ushort_t u) {
    union { u32 u; float f; } v; v.u = ((u32)u) << 16; return v.f;
}
__device__ __forceinline__ void glds16(const void* g, void* l) {
    __builtin_amdgcn_global_load_lds((const __attribute__((address_space(1))) u32*)g,
                                     (__attribute__((address_space(3))) u32*)l,
                                     16, 0, 0);
}
__device__ __forceinline__ f32x4 mfma16(short8 a, short8 b, f32x4 c) {
    return __builtin_amdgcn_mfma_f32_16x16x32_bf16(a, b, c, 0, 0, 0);
}

// ---------------------------------------------------------------------------
// 128x128 MFMA tile body (shared by gemm_bt / fusew). C = A @ B^T (+bias),
// bf16 out via LDS-coalesced epilogue. Rows covered by grid; N mult of 8.
// ---------------------------------------------------------------------------
__device__ __forceinline__ void tile128(
    const ushort_t* __restrict__ A, const ushort_t* __restrict__ B,
    ushort_t* __restrict__ Cp, int N, int K, const float* __restrict__ biasc,
    int m0, int n0, ushort_t* As, ushort_t* Bs, ushort_t* Cs)
{
    int t = threadIdx.x;
    int sr = t >> 2, sk = (t & 3) * 8;
    int wv = t >> 6, lane = t & 63;
    int wr = (wv >> 1) * 64, wc = (wv & 1) * 64;
    int lr = lane & 15, lq = lane >> 4;

    f32x4 acc[4][4];
#pragma unroll
    for (int i = 0; i < 4; ++i)
#pragma unroll
        for (int j = 0; j < 4; ++j) acc[i][j] = (f32x4){0.f, 0.f, 0.f, 0.f};

    for (int k0 = 0; k0 < K; k0 += 32) {
        glds16(A + (long)(m0 + sr) * K + k0 + sk,      (void*)(As + t * 8));
        glds16(A + (long)(m0 + sr + 64) * K + k0 + sk, (void*)(As + (t + 256) * 8));
        glds16(B + (long)(n0 + sr) * K + k0 + sk,      (void*)(Bs + t * 8));
        glds16(B + (long)(n0 + sr + 64) * K + k0 + sk, (void*)(Bs + (t + 256) * 8));
        __syncthreads();
        short8 af[4], bfr[4];
#pragma unroll
        for (int i = 0; i < 4; ++i)
            af[i] = *(const short8*)&As[(wr + i * 16 + lr) * 32 + lq * 8];
#pragma unroll
        for (int j = 0; j < 4; ++j)
            bfr[j] = *(const short8*)&Bs[(wc + j * 16 + lr) * 32 + lq * 8];
#pragma unroll
        for (int i = 0; i < 4; ++i)
#pragma unroll
            for (int j = 0; j < 4; ++j)
                acc[i][j] = mfma16(af[i], bfr[j], acc[i][j]);
        __syncthreads();
    }

    ushort_t* Cw = Cs + wv * 16 * 80;
#pragma unroll
    for (int i = 0; i < 4; ++i) {
#pragma unroll
        for (int j = 0; j < 4; ++j) {
            int colg = n0 + wc + j * 16 + lr;
            float bb = (biasc && colg < N) ? biasc[colg] : 0.f;
#pragma unroll
            for (int r = 0; r < 4; ++r)
                Cw[(lq * 4 + r) * 80 + j * 16 + lr] = f2b(acc[i][j][r] + bb);
        }
        __syncthreads();
#pragma unroll
        for (int rr = 0; rr < 2; ++rr) {
            int c = lane + 64 * rr;
            int row = c >> 3, g8 = c & 7;
            uint4 u = *(const uint4*)&Cw[row * 80 + g8 * 8];
            int colg = n0 + wc + g8 * 8;
            int rowg = m0 + wr + i * 16 + row;
            if (colg < N) *(uint4*)&Cp[(long)rowg * N + colg] = u;
        }
        __syncthreads();
    }
}

__global__ __launch_bounds__(256) void gemm_bt(
    const ushort_t* __restrict__ A, const ushort_t* __restrict__ B,
    ushort_t* __restrict__ C, int N, int K, const float* __restrict__ biasc)
{
    __shared__ ushort_t As[128 * 32], Bs[128 * 32];
    __shared__ __align__(16) ushort_t Cs[4 * 16 * 80];
    tile128(A, B, C, N, K, biasc, blockIdx.y * 128, blockIdx.x * 128, As, Bs, Cs);
}

// z<6:  Fqc[l]   = (Wo_s[l] @ Wq_c[l])^T      = Wq_c_t[l]      @ Wo_sp[l]^T
// z>=6: Fqkv[zz] = (Wo_c[l] @ W{m}_s[l+1])^T  = W{m}_s_t[l+1]  @ Wo_cp[l]^T
__global__ __launch_bounds__(256) void fusew(
    const ushort_t* __restrict__ W8t, const ushort_t* __restrict__ Wo_sp,
    const ushort_t* __restrict__ Wo_cp, ushort_t* __restrict__ Fqc_t,
    ushort_t* __restrict__ Fqkv_t)
{
    __shared__ ushort_t As[128 * 32], Bs[128 * 32];
    __shared__ __align__(16) ushort_t Cs[4 * 16 * 80];
    int z = blockIdx.z;
    const ushort_t *A, *B; ushort_t* C;
    if (z < 6)      { A = W8t + (long)(24 + z) * S2; B = Wo_sp + (long)z * S2; C = Fqc_t + (long)z * S2; }
    else { int zz = z - 6, l = zz / 3, m = zz % 3;
           A = W8t + (long)(m * 6 + l + 1) * S2; B = Wo_cp + (long)l * S2; C = Fqkv_t + (long)zz * S2; }
    tile128(A, B, C, 512, 512, nullptr, blockIdx.y * 128, blockIdx.x * 128, As, Bs, Cs);
}

// ---------------------------------------------------------------------------
// prep: z1 48x[512,512]^T bf16; z2 Wf^T padded; z3 plain Wo_s/Wo_c bf16;
// z4 Kin/Vin bf16; z5 embed+PE; z6 gq = g @ Wg_c (fp32). One launch.
// ---------------------------------------------------------------------------
__global__ __launch_bounds__(256) void prep(
    const int* __restrict__ x, const float* __restrict__ emb,
    const float* __restrict__ Wq_s, const float* __restrict__ Wk_s,
    const float* __restrict__ Wv_s, const float* __restrict__ Wo_s,
    const float* __restrict__ Wq_c, const float* __restrict__ Wg_c,
    const float* __restrict__ Wk_c, const float* __restrict__ Wv_c,
    const float* __restrict__ Wo_c, const float* __restrict__ Wf,
    const float* __restrict__ Kin, const float* __restrict__ Vin,
    const float* __restrict__ g,
    ushort_t* __restrict__ W8t, ushort_t* __restrict__ Wf_t,
    ushort_t* __restrict__ Wo_sp, ushort_t* __restrict__ Wo_cp,
    ushort_t* __restrict__ K_bf, ushort_t* __restrict__ V_bf,
    ushort_t* __restrict__ act0, float* __restrict__ gq)
{
    __shared__ float tile[64][65];
    int bid = blockIdx.x, t = threadIdx.x;
    if (bid < 3072) {
        int mat = bid >> 6, wsel = mat / 6, l = mat % 6;
        const float* src = (wsel == 0) ? Wq_s : (wsel == 1) ? Wk_s : (wsel == 2) ? Wv_s :
                           (wsel == 3) ? Wo_s : (wsel == 4) ? Wq_c : (wsel == 5) ? Wk_c :
                           (wsel == 6) ? Wv_c : Wo_c;
        src += (long)l * S2;
        ushort_t* dst = W8t + (long)mat * S2;
        int within = bid & 63;
        int n0 = (within & 7) * 64, k0 = (within >> 3) * 64;
        for (int e = t; e < 4096; e += 256) {
            int r = e >> 6, c = e & 63;
            tile[r][c] = src[(long)(k0 + r) * 512 + n0 + c];
        }
        __syncthreads();
        for (int e = t; e < 4096; e += 256) {
            int r = e >> 6, c = e & 63;
            dst[(long)(n0 + r) * 512 + k0 + c] = f2b(tile[c][r]);
        }
    } else if (bid < 4336) {
        int id = bid - 3072;
        int n0 = (id % 158) * 64, k0 = (id / 158) * 64;
        for (int e = t; e < 4096; e += 256) {
            int r = e >> 6, c = e & 63;
            int n = n0 + c;
            tile[r][c] = (n < 10000) ? Wf[(long)(k0 + r) * 10000 + n] : 0.f;
        }
        __syncthreads();
        for (int e = t; e < 4096; e += 256) {
            int r = e >> 6, c = e & 63;
            Wf_t[(long)(n0 + r) * 512 + k0 + c] = f2b(tile[c][r]);
        }
    } else if (bid < 7408) {
        long i = (long)(bid - 4336) * 1024 + t * 4;
        const float* s; ushort_t* o; long off;
        if (i < 6L * S2) { s = Wo_s; o = Wo_sp; off = i; }
        else             { s = Wo_c; o = Wo_cp; off = i - 6L * S2; }
        float4 v = *(const float4*)(s + off);
        ushort4 u; u.x = f2b(v.x); u.y = f2b(v.y); u.z = f2b(v.z); u.w = f2b(v.w);
        *(ushort4*)(o + off) = u;
    } else if (bid < 13680) {
        long i = (long)(bid - 7408) * 1024 + t * 4;
        const float* s; ushort_t* o; long off;
        if (i < 3211264L) { s = Kin; o = K_bf; off = i; }
        else              { s = Vin; o = V_bf; off = i - 3211264L; }
        float4 v = *(const float4*)(s + off);
        ushort4 u; u.x = f2b(v.x); u.y = f2b(v.y); u.z = f2b(v.z); u.w = f2b(v.w);
        *(ushort4*)(o + off) = u;
    } else if (bid < 17776) {
        long i = (long)(bid - 13680) * 256 + t;
        int d = (int)(i & 511);
        long tok = i >> 9;
        int s = (int)(tok & 63);
        int id = x[tok];
        int j = d >> 1;
        double ang = (double)s * exp(-log(10000.0) * (2.0 * j) / 512.0);
        float pe = (d & 1) ? (float)cos(ang) : (float)sin(ang);
        act0[i] = f2b(emb[(long)id * 512 + d] + pe);
    } else {
        __shared__ float gs[512];
        int id = bid - 17776;           // [0,384)
        int lb = id >> 1, half = id & 1;
        int l = lb >> 5, b = lb & 31;
        for (int i = t; i < 512; i += 256) gs[i] = g[b * 512 + i];
        __syncthreads();
        int o = half * 256 + t;
        const float* wcol = Wg_c + (long)l * S2 + o;
        float acc = 0.f;
#pragma unroll 8
        for (int i = 0; i < 512; ++i) acc += gs[i] * wcol[(long)i * 512];
        gq[((long)l * 32 + b) * 512 + o] = acc;
    }
}

// ---------------------------------------------------------------------------
// layer_self: per (b,h): q/k/v = act_b @ W slices (MFMA, W staged in LDS),
// causal attention (MFMA scores + fp32 softmax + MFMA PV), attnout bf16.
// ---------------------------------------------------------------------------
__global__ __launch_bounds__(256, 1) void layer_self(
    const ushort_t* __restrict__ act,
    const ushort_t* __restrict__ Wq, const ushort_t* __restrict__ Wk,
    const ushort_t* __restrict__ Wv, ushort_t* __restrict__ attnout)
{
    __shared__ __align__(16) char smem[111616];
    ushort_t* Wst = (ushort_t*)smem;             // [64][520]
    ushort_t* Qs  = (ushort_t*)(smem + 66560);   // [64][72]  (P after softmax)
    ushort_t* Ks  = (ushort_t*)(smem + 75776);   // [64][72]
    ushort_t* Vt  = (ushort_t*)(smem + 84992);   // [64][72]  (transposed)
    float*    Ss  = (float*)(smem + 94208);      // [64][68]

    int b = blockIdx.x >> 3, h = blockIdx.x & 7;
    int t = threadIdx.x, wv = t >> 6, lane = t & 63;
    int lr = lane & 15, lq = lane >> 4;
    const ushort_t* actb = act + (long)b * 64 * 512;

    for (int mat = 0; mat < 3; ++mat) {
        const ushort_t* W = ((mat == 0) ? Wq : (mat == 1) ? Wk : Wv) + h * 64 * 512;
        __syncthreads();
#pragma unroll
        for (int i = 0; i < 16; ++i) {
            int row = i * 4 + wv;
            glds16(W + row * 512 + lane * 8, Wst + row * 520 + lane * 8);
        }
        __syncthreads();
        f32x4 acc[4];
#pragma unroll
        for (int j = 0; j < 4; ++j) acc[j] = (f32x4){0.f, 0.f, 0.f, 0.f};
        const ushort_t* arow = actb + (wv * 16 + lr) * 512;
#pragma unroll 4
        for (int k = 0; k < 16; ++k) {
            short8 a = *(const short8*)(arow + k * 32 + lq * 8);
#pragma unroll
            for (int j = 0; j < 4; ++j) {
                short8 bb = *(const short8*)&Wst[(j * 16 + lr) * 520 + k * 32 + lq * 8];
                acc[j] = mfma16(a, bb, acc[j]);
            }
        }
        if (mat == 2) {
#pragma unroll
            for (int j = 0; j < 4; ++j)
#pragma unroll
                for (int r = 0; r < 4; ++r)
                    Vt[(j * 16 + lr) * 72 + wv * 16 + lq * 4 + r] = f2b(acc[j][r]);
        } else {
            ushort_t* Dst = (mat == 0) ? Qs : Ks;
#pragma unroll
            for (int j = 0; j < 4; ++j)
#pragma unroll
                for (int r = 0; r < 4; ++r)
                    Dst[(wv * 16 + lq * 4 + r) * 72 + j * 16 + lr] = f2b(acc[j][r]);
        }
    }
    __syncthreads();

    // scores S = Q @ K^T
    f32x4 sc[4];
#pragma unroll
    for (int j = 0; j < 4; ++j) sc[j] = (f32x4){0.f, 0.f, 0.f, 0.f};
#pragma unroll
    for (int k2 = 0; k2 < 2; ++k2) {
        short8 a = *(const short8*)&Qs[(wv * 16 + lr) * 72 + k2 * 32 + lq * 8];
#pragma unroll
        for (int j = 0; j < 4; ++j) {
            short8 bb = *(const short8*)&Ks[(j * 16 + lr) * 72 + k2 * 32 + lq * 8];
            sc[j] = mfma16(a, bb, sc[j]);
        }
    }
#pragma unroll
    for (int j = 0; j < 4; ++j)
#pragma unroll
        for (int r = 0; r < 4; ++r)
            Ss[(wv * 16 + lq * 4 + r) * 68 + j * 16 + lr] = sc[j][r];
    __syncthreads();

    // causal softmax; P (bf16) overwrites Qs
    for (int rr = 0; rr < 16; ++rr) {
        int r = wv * 16 + rr;
        float sv = (lane <= r) ? Ss[r * 68 + lane] * 0.125f : -INFINITY;
        float m = sv;
        for (int off = 32; off; off >>= 1) m = fmaxf(m, __shfl_xor(m, off));
        float p = __expf(sv - m);
        float su = p;
        for (int off = 32; off; off >>= 1) su += __shfl_xor(su, off);
        Qs[r * 72 + lane] = f2b(p / su);
    }
    __syncthreads();

    // O = P @ V  (B operand = Vt[d][key])
    f32x4 ov[4];
#pragma unroll
    for (int j = 0; j < 4; ++j) ov[j] = (f32x4){0.f, 0.f, 0.f, 0.f};
#pragma unroll
    for (int k2 = 0; k2 < 2; ++k2) {
        short8 a = *(const short8*)&Qs[(wv * 16 + lr) * 72 + k2 * 32 + lq * 8];
#pragma unroll
        for (int j = 0; j < 4; ++j) {
            short8 bb = *(const short8*)&Vt[(j * 16 + lr) * 72 + k2 * 32 + lq * 8];
            ov[j] = mfma16(a, bb, ov[j]);
        }
    }
    long obase = ((long)b * 64) * 512 + h * 64;
#pragma unroll
    for (int j = 0; j < 4; ++j)
#pragma unroll
        for (int r = 0; r < 4; ++r)
            attnout[obase + (long)(wv * 16 + lq * 4 + r) * 512 + j * 16 + lr] = f2b(ov[j][r]);
}

// ---------------------------------------------------------------------------
// layer_cross: per (b,h): qc = attnout_b @ Fqc + gq; kc/vc = K_b/V_b @ W
// slices (in-kernel, 208-row padded); scores+softmax+PV via MFMA.
// ---------------------------------------------------------------------------
__global__ __launch_bounds__(256, 1) void layer_cross(
    const ushort_t* __restrict__ attnout, const ushort_t* __restrict__ Kb,
    const ushort_t* __restrict__ Vb, const ushort_t* __restrict__ Fqc,
    const ushort_t* __restrict__ Wkc, const ushort_t* __restrict__ Wvc,
    const float* __restrict__ gql, ushort_t* __restrict__ crossout)
{
    __shared__ __align__(16) char smem[134400];
    ushort_t* Wst = (ushort_t*)smem;             // [64][520] weight stage
    float*    Ss  = (float*)smem;                // [64][216] scores (after weights dead)
    ushort_t* Qs  = (ushort_t*)(smem + 66560);   // [64][72]
    ushort_t* Kc  = (ushort_t*)(smem + 75776);   // [208][72]; Pb [64][224] after
    ushort_t* Pb  = Kc;
    ushort_t* Vt  = (ushort_t*)(smem + 105728);  // [64][224]

    int b = blockIdx.x >> 3, h = blockIdx.x & 7;
    int t = threadIdx.x, wv = t >> 6, lane = t & 63;
    int lr = lane & 15, lq = lane >> 4;
    const ushort_t* atb = attnout + (long)b * 64 * 512;
    const ushort_t* Kbb = Kb + (long)b * 196 * 512;
    const ushort_t* Vbb = Vb + (long)b * 196 * 512;

    // Phase A: qc
    {
        const ushort_t* W = Fqc + h * 64 * 512;
#pragma unroll
        for (int i = 0; i < 16; ++i) {
            int row = i * 4 + wv;
            glds16(W + row * 512 + lane * 8, Wst + row * 520 + lane * 8);
        }
        __syncthreads();
        f32x4 acc[4];
#pragma unroll
        for (int j = 0; j < 4; ++j) acc[j] = (f32x4){0.f, 0.f, 0.f, 0.f};
        const ushort_t* arow = atb + (wv * 16 + lr) * 512;
#pragma unroll 4
        for (int k = 0; k < 16; ++k) {
            short8 a = *(const short8*)(arow + k * 32 + lq * 8);
#pragma unroll
            for (int j = 0; j < 4; ++j) {
                short8 bb = *(const short8*)&Wst[(j * 16 + lr) * 520 + k * 32 + lq * 8];
                acc[j] = mfma16(a, bb, acc[j]);
            }
        }
#pragma unroll
        for (int j = 0; j < 4; ++j)
#pragma unroll
            for (int r = 0; r < 4; ++r) {
                int col = j * 16 + lr;
                Qs[(wv * 16 + lq * 4 + r) * 72 + col] =
                    f2b(acc[j][r] + gql[b * 512 + h * 64 + col]);
            }
    }
    // Phase B: kc then vc (rows padded to 208; garbage rows masked downstream)
#pragma unroll
    for (int mat = 0; mat < 2; ++mat) {
        const ushort_t* W = ((mat == 0) ? Wkc : Wvc) + h * 64 * 512;
        const ushort_t* Src = (mat == 0) ? Kbb : Vbb;
        __syncthreads();
#pragma unroll
        for (int i = 0; i < 16; ++i) {
            int row = i * 4 + wv;
            glds16(W + row * 512 + lane * 8, Wst + row * 520 + lane * 8);
        }
        __syncthreads();
        for (int rt = wv; rt < 13; rt += 4) {
            f32x4 acc[4];
#pragma unroll
            for (int j = 0; j < 4; ++j) acc[j] = (f32x4){0.f, 0.f, 0.f, 0.f};
            const ushort_t* arow = Src + (long)(rt * 16 + lr) * 512;
#pragma unroll 4
            for (int k = 0; k < 16; ++k) {
                short8 a = *(const short8*)(arow + k * 32 + lq * 8);
#pragma unroll
                for (int j = 0; j < 4; ++j) {
                    short8 bb = *(const short8*)&Wst[(j * 16 + lr) * 520 + k * 32 + lq * 8];
                    acc[j] = mfma16(a, bb, acc[j]);
                }
            }
            if (mat == 0) {
#pragma unroll
                for (int j = 0; j < 4; ++j)
#pragma unroll
                    for (int r = 0; r < 4; ++r)
                        Kc[(rt * 16 + lq * 4 + r) * 72 + j * 16 + lr] = f2b(acc[j][r]);
            } else {
#pragma unroll
                for (int j = 0; j < 4; ++j)
#pragma unroll
                    for (int r = 0; r < 4; ++r)
                        Vt[(j * 16 + lr) * 224 + rt * 16 + lq * 4 + r] = f2b(acc[j][r]);
            }
        }
    }
    __syncthreads();
    // zero Vt pad cols 196..223 (kill garbage incl. NaN before PV MFMA)
    for (int e = t; e < 64 * 28; e += 256) Vt[(e / 28) * 224 + 196 + (e % 28)] = 0;

    // Phase C: S = Qc @ Kc^T  (64 x 208)
    f32x4 sc[13];
#pragma unroll
    for (int ct = 0; ct < 13; ++ct) sc[ct] = (f32x4){0.f, 0.f, 0.f, 0.f};
#pragma unroll
    for (int k2 = 0; k2 < 2; ++k2) {
        short8 a = *(const short8*)&Qs[(wv * 16 + lr) * 72 + k2 * 32 + lq * 8];
#pragma unroll
        for (int ct = 0; ct < 13; ++ct) {
            short8 bb = *(const short8*)&Kc[(ct * 16 + lr) * 72 + k2 * 32 + lq * 8];
            sc[ct] = mfma16(a, bb, sc[ct]);
        }
    }
#pragma unroll
    for (int ct = 0; ct < 13; ++ct)
#pragma unroll
        for (int r = 0; r < 4; ++r)
            Ss[(wv * 16 + lq * 4 + r) * 216 + ct * 16 + lr] = sc[ct][r];
    __syncthreads();

    // Phase D: softmax over 196 cols; P bf16 into Kc region (+zero pad cols)
    for (int rr = 0; rr < 16; ++rr) {
        int r = wv * 16 + rr;
        float v0 = Ss[r * 216 + lane] * 0.125f;
        float v1 = Ss[r * 216 + 64 + lane] * 0.125f;
        float v2 = Ss[r * 216 + 128 + lane] * 0.125f;
        float v3 = (lane < 4) ? Ss[r * 216 + 192 + lane] * 0.125f : -INFINITY;
        float m = fmaxf(fmaxf(v0, v1), fmaxf(v2, v3));
        for (int off = 32; off; off >>= 1) m = fmaxf(m, __shfl_xor(m, off));
        float e0 = __expf(v0 - m), e1 = __expf(v1 - m), e2 = __expf(v2 - m);
        float e3 = (lane < 4) ? __expf(v3 - m) : 0.f;
        float su = e0 + e1 + e2 + e3;
        for (int off = 32; off; off >>= 1) su += __shfl_xor(su, off);
        float inv = 1.f / su;
        Pb[r * 224 + lane]       = f2b(e0 * inv);
        Pb[r * 224 + 64 + lane]  = f2b(e1 * inv);
        Pb[r * 224 + 128 + lane] = f2b(e2 * inv);
        if (lane < 4)  Pb[r * 224 + 192 + lane] = f2b(e3 * inv);
        if (lane < 28) Pb[r * 224 + 196 + lane] = 0;
    }
    __syncthreads();

    // Phase E: O = P @ Vc  (K = 224)
    f32x4 ov[4];
#pragma unroll
    for (int j = 0; j < 4; ++j) ov[j] = (f32x4){0.f, 0.f, 0.f, 0.f};
#pragma unroll
    for (int k2 = 0; k2 < 7; ++k2) {
        short8 a = *(const short8*)&Pb[(wv * 16 + lr) * 224 + k2 * 32 + lq * 8];
#pragma unroll
        for (int j = 0; j < 4; ++j) {
            short8 bb = *(const short8*)&Vt[(j * 16 + lr) * 224 + k2 * 32 + lq * 8];
            ov[j] = mfma16(a, bb, ov[j]);
        }
    }
    long obase = ((long)b * 64) * 512 + h * 64;
#pragma unroll
    for (int j = 0; j < 4; ++j)
#pragma unroll
        for (int r = 0; r < 4; ++r)
            crossout[obase + (long)(wv * 16 + lq * 4 + r) * 512 + j * 16 + lr] = f2b(ov[j][r]);
}

// ---------------------------------------------------------------------------
// Softmax over bf16 logits -> fp32 probs. One block per row.
// ---------------------------------------------------------------------------
__global__ __launch_bounds__(256) void softmax_bf(const ushort_t* __restrict__ lg,
                                                  float* __restrict__ out)
{
    __shared__ float red[8];
    long row = blockIdx.x;
    const ushort_t* p = lg + row * 10000L;
    float* po = out + row * 10000L;
    int t = threadIdx.x;
    int w = t >> 6, lane = t & 63;
    float vals[40];
    float mx = -INFINITY;
#pragma unroll
    for (int ii = 0; ii < 40; ++ii) {
        int c = t + (ii << 8);
        if (c < 10000) { float v = b2f(p[c]); vals[ii] = v; mx = fmaxf(mx, v); }
        else vals[ii] = -INFINITY;
    }
    for (int off = 32; off; off >>= 1) mx = fmaxf(mx, __shfl_xor(mx, off));
    if (lane == 0) red[w] = mx;
    __syncthreads();
    mx = fmaxf(fmaxf(red[0], red[1]), fmaxf(red[2], red[3]));
    float s = 0.f;
#pragma unroll
    for (int ii = 0; ii < 40; ++ii) {
        float e = __expf(vals[ii] - mx);
        vals[ii] = e;
        s += e;
    }
    for (int off = 32; off; off >>= 1) s += __shfl_xor(s, off);
    if (lane == 0) red[4 + w] = s;
    __syncthreads();
    s = red[4] + red[5] + red[6] + red[7];
    float inv = 1.0f / s;
#pragma unroll
    for (int ii = 0; ii < 40; ++ii) {
        int c = t + (ii << 8);
        if (c < 10000) po[c] = vals[ii] * inv;
    }
}

// ---------------------------------------------------------------------------
extern "C" void kernel_launch(void* const* d_in, const int* in_sizes, int n_in,
                              void* d_out, int out_size, void* d_ws, size_t ws_size,
                              hipStream_t stream)
{
    const int*   x    = (const int*)d_in[0];
    const float* Kin  = (const float*)d_in[1];
    const float* Vin  = (const float*)d_in[2];
    const float* g    = (const float*)d_in[3];
    const float* emb  = (const float*)d_in[5];
    const float* Wq_s = (const float*)d_in[6];
    const float* Wk_s = (const float*)d_in[7];
    const float* Wv_s = (const float*)d_in[8];
    const float* Wo_s = (const float*)d_in[9];
    const float* Wq_c = (const float*)d_in[10];
    const float* Wg_c = (const float*)d_in[11];
    const float* Wk_c = (const float*)d_in[12];
    const float* Wv_c = (const float*)d_in[13];
    const float* Wo_c = (const float*)d_in[14];
    const float* Wf   = (const float*)d_in[15];
    const float* bf   = (const float*)d_in[16];
    float* out = (float*)d_out;

    float* gq = (float*)d_ws;                                // [6,32,512] fp32
    ushort_t* act0     = (ushort_t*)(gq + 98304);            // [2048,512]
    ushort_t* crossout = act0 + 1048576;
    ushort_t* attnout  = crossout + 1048576;
    ushort_t* K_bf     = attnout + 1048576;                  // [6272,512]
    ushort_t* V_bf     = K_bf + 3211264;
    ushort_t* W8t      = V_bf + 3211264;                     // 48 x [512,512]^T
    ushort_t* Wf_t     = W8t + 48L * S2;                     // [10112,512]
    ushort_t* Wo_sp    = Wf_t + 5177344;                     // 6 x plain
    ushort_t* Wo_cp    = Wo_sp + 6L * S2;                    // 6 x plain
    ushort_t* Fqc_t    = Wo_cp + 6L * S2;                    // 6 x [512,512]
    ushort_t* Fqkv_t   = Fqc_t + 6L * S2;                    // 15 x [512,512]
    ushort_t* Wfin_t   = Fqkv_t + 15L * S2;                  // [10112,512]
    ushort_t* logits   = W8t;                                // reuse after layers

    prep<<<18160, 256, 0, stream>>>(x, emb, Wq_s, Wk_s, Wv_s, Wo_s, Wq_c, Wg_c,
                                    Wk_c, Wv_c, Wo_c, Wf, Kin, Vin, g,
                                    W8t, Wf_t, Wo_sp, Wo_cp, K_bf, V_bf, act0, gq);
    fusew<<<dim3(4, 4, 21), 256, 0, stream>>>(W8t, Wo_sp, Wo_cp, Fqc_t, Fqkv_t);
    // Wfin = (Wo_c[5] @ Wf)^T = Wf_t @ Wo_cp[5]^T  -> [10112,512]
    gemm_bt<<<dim3(4, 79, 1), 256, 0, stream>>>(Wf_t, Wo_cp + 5L * S2, Wfin_t,
                                                512, 512, nullptr);

    for (int l = 0; l < 6; ++l) {
        const ushort_t *A, *Bq, *Bk, *Bv;
        if (l == 0) {
            A = act0;
            Bq = W8t + 0L * 6 * S2; Bk = W8t + 1L * 6 * S2; Bv = W8t + 2L * 6 * S2;
        } else {
            A = crossout;
            Bq = Fqkv_t + (long)((l - 1) * 3) * S2;
            Bk = Bq + S2; Bv = Bq + 2 * S2;
        }
        layer_self<<<256, 256, 0, stream>>>(A, Bq, Bk, Bv, attnout);
        layer_cross<<<256, 256, 0, stream>>>(attnout, K_bf, V_bf,
                                             Fqc_t + (long)l * S2,
                                             W8t + (long)(5 * 6 + l) * S2,
                                             W8t + (long)(6 * 6 + l) * S2,
                                             gq + (long)l * 16384, crossout);
    }

    gemm_bt<<<dim3(79, 16, 1), 256, 0, stream>>>(crossout, Wfin_t, logits,
                                                 10000, 512, bf);
    softmax_bf<<<2048, 256, 0, stream>>>(logits, out);
}